// Round 1
// baseline (225.017 us; speedup 1.0000x reference)
//
#include <hip/hip_runtime.h>
#include <cstdint>
#include <cstddef>

// Problem constants (b=1)
#define LL 2048     // sequence length
#define DD 1024     // model dim
#define NH 16       // heads
#define DH 64       // head dim
#define RSEG 32     // LL/64 chunks

using u16 = unsigned short;
typedef __attribute__((ext_vector_type(8))) __bf16 bf16x8;
typedef __attribute__((ext_vector_type(4))) float f32x4;
typedef __attribute__((ext_vector_type(8))) u16 u16x8;
typedef __attribute__((ext_vector_type(4))) u16 u16x4;
typedef __attribute__((ext_vector_type(4))) float f32x4v;

static __device__ __forceinline__ u16 f2bf(float f) {
  union { float f; unsigned u; } a; a.f = f;
  unsigned u = a.u;
  return (u16)((u + 0x7fffu + ((u >> 16) & 1u)) >> 16);
}

static __device__ __forceinline__ f32x4 mfma16(bf16x8 a, bf16x8 b, f32x4 c) {
  return __builtin_amdgcn_mfma_f32_16x16x32_bf16(a, b, c, 0, 0, 0);
}

#define GLOAD_LDS16(gsrc, ldst)                                                        \
  __builtin_amdgcn_global_load_lds((const __attribute__((address_space(1))) void*)(gsrc), \
                                   (__attribute__((address_space(3))) void*)(ldst), 16, 0, 0)

// Stage a 64x64 bf16 tile from row-major global (row stride rs elems) into MFMA
// layout: byte = rb*2048 + kh*1024 + kg*256 + lr*16  (rb=row/16, kh=col/32, kg=(col%32)/8, lr=row%16)
static __device__ __forceinline__ void stage64(const u16* g, int rs, u16* lds, int wave, int lane) {
  int lr = lane & 15, kg = lane >> 4;
#pragma unroll
  for (int i = 0; i < 2; ++i) {
    int idx = wave * 2 + i;
    int rb = idx >> 1, kh = idx & 1;
    const u16* src = g + (size_t)(rb * 16 + lr) * rs + kh * 32 + kg * 8;
    GLOAD_LDS16(src, (char*)lds + idx * 1024);
  }
}

// Read one 16x32 A/B fragment (rows rb*16.., k = t*32..t*32+31)
static __device__ __forceinline__ bf16x8 frag64(const u16* lds, int rb, int t, int lane) {
  return *(const bf16x8*)((const char*)lds + rb * 2048 + t * 1024 + (lane >> 4) * 256 +
                          (lane & 15) * 16);
}

// ---------------- fp32 -> bf16 cast ----------------
__global__ __launch_bounds__(256) void k_cast(const float* __restrict__ src, u16* __restrict__ dst,
                                              int n) {
  int i = (blockIdx.x * 256 + threadIdx.x) * 4;
  if (i >= n) return;
  f32x4v v = *(const f32x4v*)(src + i);
  u16x4 o;
#pragma unroll
  for (int t = 0; t < 4; ++t) o[t] = f2bf(v[t]);
  *(u16x4*)(dst + i) = o;
}

// ---------------- GEMM: C[M,N] = A[M,K] * B[N,K]^T (both bf16 row-major) ----------------
// 128x128 tile, BK=32, 4 waves (2x2 quadrants of 64x64), global_load_lds staging.
template <bool WF32>
__global__ __launch_bounds__(256) void k_gemm(const u16* __restrict__ A, const u16* __restrict__ Ball,
                                              u16* __restrict__ Cb, float* __restrict__ Cf) {
  __shared__ u16 lA[128 * 32];
  __shared__ u16 lB[128 * 32];
  const int tid = threadIdx.x, lane = tid & 63, wave = tid >> 6;
  const int lr = lane & 15, kg = lane >> 4;
  const int wr = wave >> 1, wc = wave & 1;
  const u16* B = Ball + (size_t)blockIdx.z * (DD * DD);
  const int brow = blockIdx.y * 128, bcol = blockIdx.x * 128;
  f32x4 acc[4][4] = {};
  for (int kt = 0; kt < DD / 32; ++kt) {
    __syncthreads();
#pragma unroll
    for (int i = 0; i < 2; ++i) {
      int rb = wave * 2 + i;
      GLOAD_LDS16(A + (size_t)(brow + rb * 16 + lr) * DD + kt * 32 + kg * 8, (char*)lA + rb * 1024);
      GLOAD_LDS16(B + (size_t)(bcol + rb * 16 + lr) * DD + kt * 32 + kg * 8, (char*)lB + rb * 1024);
    }
    __syncthreads();
    bf16x8 af[4], bb[4];
#pragma unroll
    for (int f = 0; f < 4; ++f) {
      af[f] = *(const bf16x8*)((const char*)lA + (wr * 4 + f) * 1024 + kg * 256 + lr * 16);
      bb[f] = *(const bf16x8*)((const char*)lB + (wc * 4 + f) * 1024 + kg * 256 + lr * 16);
    }
#pragma unroll
    for (int i = 0; i < 4; ++i)
#pragma unroll
      for (int j = 0; j < 4; ++j) acc[i][j] = mfma16(af[i], bb[j], acc[i][j]);
  }
  u16* Co = Cb + (size_t)blockIdx.z * ((size_t)LL * DD);
#pragma unroll
  for (int i = 0; i < 4; ++i)
#pragma unroll
    for (int j = 0; j < 4; ++j)
#pragma unroll
      for (int r = 0; r < 4; ++r) {
        int row = brow + wr * 64 + i * 16 + kg * 4 + r;
        int col = bcol + wc * 64 + j * 16 + lr;
        if constexpr (WF32)
          Cf[(size_t)row * DD + col] = acc[i][j][r];
        else
          Co[(size_t)row * DD + col] = f2bf(acc[i][j][r]);
      }
}

// ---------------- transpose k/v per head: [m][h*64+d] -> T[h][d][m] ----------------
__global__ __launch_bounds__(256) void k_transpose(const u16* __restrict__ kb,
                                                   const u16* __restrict__ vb, u16* __restrict__ kT,
                                                   u16* __restrict__ vT) {
  __shared__ u16 tile[64][72];
  int bid = blockIdx.x;  // = ((mt*16)+h)*2 + which
  int mt = bid >> 5, h = (bid >> 1) & 15, wch = bid & 1;
  const u16* src = wch ? vb : kb;
  u16* dst = wch ? vT : kT;
  int tid = threadIdx.x;
  int m = tid >> 3, d0 = (tid & 7) * 8;
#pragma unroll
  for (int i = 0; i < 2; ++i) {
    u16x8 v = *(const u16x8*)(src + (size_t)(mt * 64 + m + i * 32) * DD + h * DH + d0);
    *(u16x8*)&tile[m + i * 32][d0] = v;
  }
  __syncthreads();
  int d = tid >> 3, m0 = (tid & 7) * 8;
#pragma unroll
  for (int i = 0; i < 2; ++i) {
    u16 tmp[8];
#pragma unroll
    for (int t = 0; t < 8; ++t) tmp[t] = tile[m0 + t][d + i * 32];
    *(u16x8*)(dst + (size_t)(h * DH + d + i * 32) * LL + mt * 64 + m0) = *(const u16x8*)tmp;
  }
}

// ---------------- scores / softmax / pcs / out_t  (one block per (h, chunk c)) ----------------
__global__ __launch_bounds__(256) void k_score(const u16* __restrict__ qb, const u16* __restrict__ kb,
                                               const u16* __restrict__ vT,
                                               const float* __restrict__ idx_dec,
                                               float* __restrict__ pcs, float* __restrict__ out_t) {
  __shared__ u16 qs[64 * 64];
  __shared__ u16 ks[64 * 64];
  __shared__ u16 vt[64 * 64];
  __shared__ u16 pt[64 * 64];
  __shared__ float ppart[4][64];
  const int tid = threadIdx.x, lane = tid & 63, wave = tid >> 6;
  const int lr = lane & 15, g = lane >> 4;
  const int c = blockIdx.x & 31, h = blockIdx.x >> 5;

  stage64(qb + (size_t)(c * 64) * DD + h * DH, DD, qs, wave, lane);

  float E4[4];
#pragma unroll
  for (int r = 0; r < 4; ++r) E4[r] = __expf(idx_dec[h * 64 + wave * 16 + g * 4 + r]);

  __syncthreads();
  bf16x8 aq0 = frag64(qs, wave, 0, lane);
  bf16x8 aq1 = frag64(qs, wave, 1, lane);

  // pass 1: softmax denominators (no max subtraction: |scores| <~ 3, fp32-safe)
  float dfull[4] = {0.f, 0.f, 0.f, 0.f}, dterr[4] = {0.f, 0.f, 0.f, 0.f};
  for (int j = 0; j <= c; ++j) {
    __syncthreads();
    stage64(kb + (size_t)(j * 64) * DD + h * DH, DD, ks, wave, lane);
    __syncthreads();
    float ev[4][4];
#pragma unroll
    for (int f = 0; f < 4; ++f) {
      f32x4 z = {0.f, 0.f, 0.f, 0.f};
      z = mfma16(aq0, frag64(ks, f, 0, lane), z);
      z = mfma16(aq1, frag64(ks, f, 1, lane), z);
#pragma unroll
      for (int r = 0; r < 4; ++r) {
        float e = __expf(z[r] * 0.125f);
        if (j == c && (f * 16 + lr) > (wave * 16 + g * 4 + r)) e = 0.f;  // causal mask
        ev[f][r] = e;
      }
    }
    bool terr = (j >= c - 1);
#pragma unroll
    for (int r = 0; r < 4; ++r) {
      float s = ev[0][r] + ev[1][r] + ev[2][r] + ev[3][r];
      s += __shfl_xor(s, 1, 64);
      s += __shfl_xor(s, 2, 64);
      s += __shfl_xor(s, 4, 64);
      s += __shfl_xor(s, 8, 64);
      dfull[r] += s;
      if (terr) dterr[r] += s;
    }
  }
  float invd[4], invdt[4];
#pragma unroll
  for (int r = 0; r < 4; ++r) {
    invd[r] = 1.f / dfull[r];
    invdt[r] = 1.f / dterr[r];
  }

  f32x4 ot[4] = {};

  // pass 2: recompute scores; accumulate pcs and out_t
  for (int j = 0; j <= c; ++j) {
    bool terr = (j >= c - 1);
    __syncthreads();
    stage64(kb + (size_t)(j * 64) * DD + h * DH, DD, ks, wave, lane);
    if (terr) stage64(vT + (size_t)(h * DH) * LL + j * 64, LL, vt, wave, lane);
    __syncthreads();
#pragma unroll
    for (int f = 0; f < 4; ++f) {
      f32x4 z = {0.f, 0.f, 0.f, 0.f};
      z = mfma16(aq0, frag64(ks, f, 0, lane), z);
      z = mfma16(aq1, frag64(ks, f, 1, lane), z);
      float part = 0.f;
#pragma unroll
      for (int r = 0; r < 4; ++r) {
        float e = __expf(z[r] * 0.125f);
        if (j == c && (f * 16 + lr) > (wave * 16 + g * 4 + r)) e = 0.f;
        part += E4[r] * (e * invd[r]);
        if (terr) {
          int col = f * 16 + lr, rowb = g * 4 + r;
          // write P_t into A-fragment layout (rows = s, k = m)
          *(u16*)((char*)pt + wave * 2048 + (col >> 3) * 256 + rowb * 16 + (col & 7) * 2) =
              f2bf(e * invdt[r]);
        }
      }
      part += __shfl_xor(part, 16, 64);
      part += __shfl_xor(part, 32, 64);
      if (g == 0) ppart[wave][f * 16 + lr] = part;
    }
    __syncthreads();
    if (tid < 64) {
      pcs[(size_t)(h * RSEG + c) * LL + j * 64 + tid] =
          ppart[0][tid] + ppart[1][tid] + ppart[2][tid] + ppart[3][tid];
    }
    if (terr) {
#pragma unroll
      for (int t = 0; t < 2; ++t) {
        bf16x8 ap = frag64(pt, wave, t, lane);
#pragma unroll
        for (int f = 0; f < 4; ++f) ot[f] = mfma16(ap, frag64(vt, f, t, lane), ot[f]);
      }
    }
  }
  for (int m = (c + 1) * 64 + tid; m < LL; m += 256)
    pcs[(size_t)(h * RSEG + c) * LL + m] = 0.f;
#pragma unroll
  for (int f = 0; f < 4; ++f)
#pragma unroll
    for (int r = 0; r < 4; ++r) {
      int srow = wave * 16 + g * 4 + r, e = f * 16 + lr;
      out_t[((size_t)(h * RSEG + c) * 64 + srow) * 64 + e] = ot[f][r];
    }
}

// ---------------- segment scan: w_i = mega*w_{i-1} + pcs_{i-1} ----------------
__global__ __launch_bounds__(256) void k_scan(const float* __restrict__ pcs,
                                              const float* __restrict__ mega_decays,
                                              float* __restrict__ w) {
  int idx = blockIdx.x * 256 + threadIdx.x;  // 16*2048
  int h = idx >> 11, m = idx & 2047;
  float mg = __expf(mega_decays[h] * 64.f);
  mg = fminf(fmaxf(mg, 0.f), 2.f);
  float carry = 0.f;
  for (int i = 0; i < RSEG; ++i) {
    size_t o = (size_t)(h * RSEG + i) * LL + m;
    w[o] = carry;
    carry = carry * mg + pcs[o];
  }
}

__global__ __launch_bounds__(256) void k_wsum(const float* __restrict__ w,
                                              float* __restrict__ inv_wsum) {
  __shared__ float red[256];
  int row = blockIdx.x;
  float s = 0.f;
  for (int m = threadIdx.x; m < LL; m += 256) s += w[(size_t)row * LL + m];
  red[threadIdx.x] = s;
  __syncthreads();
  for (int st = 128; st > 0; st >>= 1) {
    if (threadIdx.x < st) red[threadIdx.x] += red[threadIdx.x + st];
    __syncthreads();
  }
  if (threadIdx.x == 0) inv_wsum[row] = 1.f / (red[0] + 1e-5f);
}

// ---------------- kv state: kvT[c][h][e][d] = sum_m wn[m] k[m,d] v[m,e] ----------------
__global__ __launch_bounds__(256) void k_kv(const u16* __restrict__ kT, const u16* __restrict__ vT,
                                            const float* __restrict__ w,
                                            const float* __restrict__ inv_wsum,
                                            u16* __restrict__ kvT) {
  __shared__ u16 kt[64 * 64];
  __shared__ u16 vt[64 * 64];
  __shared__ float wn[64];
  __shared__ float kvt[64 * 65];
  const int tid = threadIdx.x, lane = tid & 63, wave = tid >> 6;
  const int lr = lane & 15, g = lane >> 4;
  const int c = blockIdx.x & 31, h = blockIdx.x >> 5;
  const float invw = inv_wsum[h * RSEG + c];
  f32x4 acc[4] = {};
  for (int j = 0; j < c; ++j) {
    __syncthreads();
    stage64(kT + (size_t)(h * DH) * LL + j * 64, LL, kt, wave, lane);
    stage64(vT + (size_t)(h * DH) * LL + j * 64, LL, vt, wave, lane);
    if (tid < 64) wn[tid] = w[(size_t)(h * RSEG + c) * LL + j * 64 + tid] * invw;
    __syncthreads();
#pragma unroll
    for (int t = 0; t < 2; ++t) {
      bf16x8 raw = frag64(kt, wave, t, lane);
      bf16x8 a;
      int m0 = t * 32 + g * 8;
#pragma unroll
      for (int i = 0; i < 8; ++i) a[i] = (__bf16)((float)raw[i] * wn[m0 + i]);
#pragma unroll
      for (int f = 0; f < 4; ++f) acc[f] = mfma16(a, frag64(vt, f, t, lane), acc[f]);
    }
  }
  __syncthreads();
#pragma unroll
  for (int f = 0; f < 4; ++f)
#pragma unroll
    for (int r = 0; r < 4; ++r) kvt[(f * 16 + lr) * 65 + wave * 16 + g * 4 + r] = acc[f][r];
  __syncthreads();
  {
    int e = tid >> 2, d0 = (tid & 3) * 16;
    u16 tmp[16];
#pragma unroll
    for (int i = 0; i < 16; ++i) tmp[i] = f2bf(kvt[e * 65 + d0 + i]);
    u16* dst = kvT + ((size_t)(c * NH + h) * 64 + e) * 64 + d0;
    *(u16x8*)dst = *(const u16x8*)tmp;
    *(u16x8*)(dst + 8) = *(const u16x8*)(tmp + 8);
  }
}

// ---------------- out_lin + mix -> y (bf16) ----------------
__global__ __launch_bounds__(256) void k_outlin(const u16* __restrict__ qb,
                                                const u16* __restrict__ kvT,
                                                const float* __restrict__ out_t,
                                                const float* __restrict__ tmix,
                                                u16* __restrict__ yb) {
  const int tid = threadIdx.x, lane = tid & 63, wave = tid >> 6;
  const int lr = lane & 15, g = lane >> 4;
  const int c = blockIdx.x & 31, h = blockIdx.x >> 5;
  bf16x8 aq[2], bk[4][2];
#pragma unroll
  for (int t = 0; t < 2; ++t)
    aq[t] = *(const bf16x8*)(qb + (size_t)(c * 64 + wave * 16 + lr) * DD + h * DH + t * 32 + g * 8);
#pragma unroll
  for (int f = 0; f < 4; ++f)
#pragma unroll
    for (int t = 0; t < 2; ++t)
      bk[f][t] =
          *(const bf16x8*)(kvT + ((size_t)(c * NH + h) * 64 + f * 16 + lr) * 64 + t * 32 + g * 8);
  f32x4 ao[4] = {};
#pragma unroll
  for (int t = 0; t < 2; ++t)
#pragma unroll
    for (int f = 0; f < 4; ++f) ao[f] = mfma16(aq[t], bk[f][t], ao[f]);
  float tw[4];
#pragma unroll
  for (int r = 0; r < 4; ++r) tw[r] = 1.f / (1.f + __expf(-tmix[wave * 16 + g * 4 + r]));
#pragma unroll
  for (int f = 0; f < 4; ++f)
#pragma unroll
    for (int r = 0; r < 4; ++r) {
      int s = wave * 16 + g * 4 + r, e = f * 16 + lr;
      float otv = out_t[((size_t)(h * RSEG + c) * 64 + s) * 64 + e];
      float yv = tw[r] * otv + (1.f - tw[r]) * ao[f][r];
      yb[(size_t)(c * 64 + s) * DD + h * DH + e] = f2bf(yv);
    }
}

// ---------------- host launch ----------------
extern "C" void kernel_launch(void* const* d_in, const int* in_sizes, int n_in, void* d_out,
                              int out_size, void* d_ws, size_t ws_size, hipStream_t stream) {
  const float* hs = (const float*)d_in[0];
  const float* Wq = (const float*)d_in[1];
  const float* Wk = (const float*)d_in[2];
  const float* Wv = (const float*)d_in[3];
  const float* Wc = (const float*)d_in[4];
  const float* tmix = (const float*)d_in[5];
  const float* idx_dec = (const float*)d_in[6];
  const float* mega = (const float*)d_in[7];
  char* ws = (char*)d_ws;

  // workspace layout (bytes). out_t / y reuse regions dead after the QKV GEMM.
  u16* hs_bf = (u16*)(ws + 0);                 // 4 MB
  u16* wq_bf = (u16*)(ws + 4194304);           // 2 MB (Wq,Wk,Wv contiguous)
  u16* wc_bf = (u16*)(ws + 12582912);          // 2 MB
  u16* q_bf = (u16*)(ws + 14680064);           // q,k,v contiguous 12 MB
  u16* k_bf = q_bf + (size_t)LL * DD;
  u16* v_bf = q_bf + 2 * (size_t)LL * DD;
  u16* kT = (u16*)(ws + 27262976);             // 4 MB
  u16* vT = (u16*)(ws + 31457280);             // 4 MB
  float* pcs = (float*)(ws + 35651584);        // 4 MB
  float* wbuf = (float*)(ws + 39845888);       // 4 MB
  float* iws = (float*)(ws + 44040192);        // 2 KB
  u16* kvT = (u16*)(ws + 44044288);            // 4 MB
  float* out_t = (float*)(ws + 0);             // 8 MB (reuses hs_bf/Wq/Wk)
  u16* y_bf = (u16*)(ws + 8388608);            // 4 MB (reuses Wv + hole)

  k_cast<<<dim3((LL * DD / 4 + 255) / 256), 256, 0, stream>>>(hs, hs_bf, LL * DD);
  k_cast<<<dim3((DD * DD / 4 + 255) / 256), 256, 0, stream>>>(Wq, wq_bf, DD * DD);
  k_cast<<<dim3((DD * DD / 4 + 255) / 256), 256, 0, stream>>>(Wk, wq_bf + DD * DD, DD * DD);
  k_cast<<<dim3((DD * DD / 4 + 255) / 256), 256, 0, stream>>>(Wv, wq_bf + 2 * DD * DD, DD * DD);
  k_cast<<<dim3((DD * DD / 4 + 255) / 256), 256, 0, stream>>>(Wc, wc_bf, DD * DD);

  k_gemm<false><<<dim3(DD / 128, LL / 128, 3), 256, 0, stream>>>(hs_bf, wq_bf, q_bf, nullptr);
  k_transpose<<<dim3(1024), 256, 0, stream>>>(k_bf, v_bf, kT, vT);
  k_score<<<dim3(512), 256, 0, stream>>>(q_bf, k_bf, vT, idx_dec, pcs, out_t);
  k_scan<<<dim3(128), 256, 0, stream>>>(pcs, mega, wbuf);
  k_wsum<<<dim3(512), 256, 0, stream>>>(wbuf, iws);
  k_kv<<<dim3(512), 256, 0, stream>>>(kT, vT, wbuf, iws, kvT);
  k_outlin<<<dim3(512), 256, 0, stream>>>(q_bf, kvT, out_t, tmix, y_bf);
  k_gemm<true><<<dim3(DD / 128, LL / 128, 1), 256, 0, stream>>>(y_bf, wc_bf, nullptr,
                                                                (float*)d_out);
  (void)in_sizes; (void)n_in; (void)out_size; (void)ws_size;
}

// Round 2
// 190.928 us; speedup vs baseline: 1.1785x; 1.1785x over previous
//
#include <hip/hip_runtime.h>
#include <cstdint>
#include <cstddef>

// Problem constants (b=1)
#define LL 2048     // sequence length
#define DD 1024     // model dim
#define NH 16       // heads
#define DH 64       // head dim
#define RSEG 32     // LL/64 chunks

using u16 = unsigned short;
typedef __attribute__((ext_vector_type(8))) __bf16 bf16x8;
typedef __attribute__((ext_vector_type(4))) float f32x4;
typedef __attribute__((ext_vector_type(8))) u16 u16x8;
typedef __attribute__((ext_vector_type(4))) u16 u16x4;
typedef __attribute__((ext_vector_type(4))) float f32x4v;

static __device__ __forceinline__ u16 f2bf(float f) {
  union { float f; unsigned u; } a; a.f = f;
  unsigned u = a.u;
  return (u16)((u + 0x7fffu + ((u >> 16) & 1u)) >> 16);
}
static __device__ __forceinline__ float bf2f(u16 x) {
  union { unsigned u; float f; } a; a.u = ((unsigned)x) << 16;
  return a.f;
}

static __device__ __forceinline__ f32x4 mfma16(bf16x8 a, bf16x8 b, f32x4 c) {
  return __builtin_amdgcn_mfma_f32_16x16x32_bf16(a, b, c, 0, 0, 0);
}

#define GLOAD_LDS16(gsrc, ldst)                                                        \
  __builtin_amdgcn_global_load_lds((const __attribute__((address_space(1))) void*)(gsrc), \
                                   (__attribute__((address_space(3))) void*)(ldst), 16, 0, 0)

// Stage a 64x64 bf16 tile from row-major global (row stride rs elems) into MFMA
// layout: byte = rb*2048 + kh*1024 + kg*256 + lr*16
static __device__ __forceinline__ void stage64(const u16* g, int rs, u16* lds, int wave, int lane) {
  int lr = lane & 15, kg = lane >> 4;
#pragma unroll
  for (int i = 0; i < 2; ++i) {
    int idx = wave * 2 + i;
    int rb = idx >> 1, kh = idx & 1;
    const u16* src = g + (size_t)(rb * 16 + lr) * rs + kh * 32 + kg * 8;
    GLOAD_LDS16(src, (char*)lds + idx * 1024);
  }
}

// Read one 16x32 A/B fragment (rows rb*16.., k = t*32..t*32+31)
static __device__ __forceinline__ bf16x8 frag64(const u16* lds, int rb, int t, int lane) {
  return *(const bf16x8*)((const char*)lds + rb * 2048 + t * 1024 + (lane >> 4) * 256 +
                          (lane & 15) * 16);
}

// ---------------- fused fp32 -> bf16 cast of all inputs ----------------
__global__ __launch_bounds__(256) void k_castall(const float* __restrict__ hs,
                                                 const float* __restrict__ Wq,
                                                 const float* __restrict__ Wk,
                                                 const float* __restrict__ Wv,
                                                 const float* __restrict__ Wc,
                                                 u16* __restrict__ hs_bf, u16* __restrict__ wq_bf,
                                                 u16* __restrict__ wc_bf) {
  int i = (blockIdx.x * 256 + threadIdx.x) * 4;  // over 6M elements
  const float* src;
  u16* dst;
  int off;
  if (i < 2097152) { src = hs; dst = hs_bf; off = i; }
  else if (i < 3145728) { src = Wq; dst = wq_bf; off = i - 2097152; }
  else if (i < 4194304) { src = Wk; dst = wq_bf + 1048576; off = i - 3145728; }
  else if (i < 5242880) { src = Wv; dst = wq_bf + 2097152; off = i - 4194304; }
  else { src = Wc; dst = wc_bf; off = i - 5242880; }
  f32x4v v = *(const f32x4v*)(src + off);
  u16x4 o;
#pragma unroll
  for (int t = 0; t < 4; ++t) o[t] = f2bf(v[t]);
  *(u16x4*)(dst + off) = o;
}

// ---------------- GEMM: C[M,N] = A[M,K] * B[N,K]^T, 128x128 tile, BK=64 ----------------
template <bool WF32>
__global__ __launch_bounds__(256) void k_gemm(const u16* __restrict__ A, const u16* __restrict__ Ball,
                                              u16* __restrict__ Cb, float* __restrict__ Cf) {
  __shared__ u16 lA[128 * 64];
  __shared__ u16 lB[128 * 64];
  const int tid = threadIdx.x, lane = tid & 63, wave = tid >> 6;
  const int lr = lane & 15, kg = lane >> 4;
  const int wr = wave >> 1, wc = wave & 1;
  const u16* B = Ball + (size_t)blockIdx.z * (DD * DD);
  const int brow = blockIdx.y * 128, bcol = blockIdx.x * 128;
  f32x4 acc[4][4] = {};
  for (int kt = 0; kt < DD / 64; ++kt) {
    __syncthreads();
#pragma unroll
    for (int i = 0; i < 4; ++i) {
      int idx = wave * 4 + i;
      int rb = idx >> 1, kh = idx & 1;
      GLOAD_LDS16(A + (size_t)(brow + rb * 16 + lr) * DD + kt * 64 + kh * 32 + kg * 8,
                  (char*)lA + rb * 2048 + kh * 1024);
      GLOAD_LDS16(B + (size_t)(bcol + rb * 16 + lr) * DD + kt * 64 + kh * 32 + kg * 8,
                  (char*)lB + rb * 2048 + kh * 1024);
    }
    __syncthreads();
    bf16x8 af[4][2], bb[4][2];
#pragma unroll
    for (int f = 0; f < 4; ++f)
#pragma unroll
      for (int t = 0; t < 2; ++t) {
        af[f][t] = *(const bf16x8*)((const char*)lA + (wr * 4 + f) * 2048 + t * 1024 + kg * 256 + lr * 16);
        bb[f][t] = *(const bf16x8*)((const char*)lB + (wc * 4 + f) * 2048 + t * 1024 + kg * 256 + lr * 16);
      }
#pragma unroll
    for (int t = 0; t < 2; ++t)
#pragma unroll
      for (int i = 0; i < 4; ++i)
#pragma unroll
        for (int j = 0; j < 4; ++j) acc[i][j] = mfma16(af[i][t], bb[j][t], acc[i][j]);
  }
  u16* Co = Cb + (size_t)blockIdx.z * ((size_t)LL * DD);
#pragma unroll
  for (int i = 0; i < 4; ++i)
#pragma unroll
    for (int j = 0; j < 4; ++j)
#pragma unroll
      for (int r = 0; r < 4; ++r) {
        int row = brow + wr * 64 + i * 16 + kg * 4 + r;
        int col = bcol + wc * 64 + j * 16 + lr;
        if constexpr (WF32)
          Cf[(size_t)row * DD + col] = acc[i][j][r];
        else
          Co[(size_t)row * DD + col] = f2bf(acc[i][j][r]);
      }
}

// ---------------- transpose k/v per head: [m][h*64+d] -> T[h][d][m] ----------------
__global__ __launch_bounds__(256) void k_transpose(const u16* __restrict__ kb,
                                                   const u16* __restrict__ vb, u16* __restrict__ kT,
                                                   u16* __restrict__ vT) {
  __shared__ u16 tile[64][72];
  int bid = blockIdx.x;
  int mt = bid >> 5, h = (bid >> 1) & 15, wch = bid & 1;
  const u16* src = wch ? vb : kb;
  u16* dst = wch ? vT : kT;
  int tid = threadIdx.x;
  int m = tid >> 3, d0 = (tid & 7) * 8;
#pragma unroll
  for (int i = 0; i < 2; ++i) {
    u16x8 v = *(const u16x8*)(src + (size_t)(mt * 64 + m + i * 32) * DD + h * DH + d0);
    *(u16x8*)&tile[m + i * 32][d0] = v;
  }
  __syncthreads();
  int d = tid >> 3, m0 = (tid & 7) * 8;
#pragma unroll
  for (int i = 0; i < 2; ++i) {
    u16 tmp[8];
#pragma unroll
    for (int t = 0; t < 8; ++t) tmp[t] = tile[m0 + t][d + i * 32];
    *(u16x8*)(dst + (size_t)(h * DH + d + i * 32) * LL + mt * 64 + m0) = *(const u16x8*)tmp;
  }
}

// ---------------- denominator partials: dpart[(h,c,sp)][row] ----------------
__global__ __launch_bounds__(256) void k_den(const u16* __restrict__ qb, const u16* __restrict__ kb,
                                             float* __restrict__ dpart) {
  __shared__ u16 qs[64 * 64];
  __shared__ u16 ks[64 * 64];
  const int tid = threadIdx.x, lane = tid & 63, wave = tid >> 6;
  const int lr = lane & 15, g = lane >> 4;
  const int x = blockIdx.x;
  const int sp = x & 3, c = (x >> 2) & 31, h = x >> 7;
  const int n = c + 1, base = n >> 2, rem = n & 3;
  const int lo = sp * base + (sp < rem ? sp : rem);
  const int cnt = base + (sp < rem ? 1 : 0);

  stage64(qb + (size_t)(c * 64) * DD + h * DH, DD, qs, wave, lane);
  __syncthreads();
  bf16x8 aq0 = frag64(qs, wave, 0, lane);
  bf16x8 aq1 = frag64(qs, wave, 1, lane);

  float dfull[4] = {0.f, 0.f, 0.f, 0.f};
  for (int t = 0; t < cnt; ++t) {
    int j = lo + t;
    __syncthreads();
    stage64(kb + (size_t)(j * 64) * DD + h * DH, DD, ks, wave, lane);
    __syncthreads();
#pragma unroll
    for (int f = 0; f < 4; ++f) {
      f32x4 z = {0.f, 0.f, 0.f, 0.f};
      z = mfma16(aq0, frag64(ks, f, 0, lane), z);
      z = mfma16(aq1, frag64(ks, f, 1, lane), z);
      float ev[4];
#pragma unroll
      for (int r = 0; r < 4; ++r) {
        float e = __expf(z[r] * 0.125f);
        if (j == c && (f * 16 + lr) > (wave * 16 + g * 4 + r)) e = 0.f;
        ev[r] = e;
      }
#pragma unroll
      for (int r = 0; r < 4; ++r) dfull[r] += ev[r];
    }
#pragma unroll
    for (int r = 0; r < 4; ++r) {
      float s = dfull[r];
      // defer reduction: keep per-lane partial, reduce once at end
      dfull[r] = s;
    }
  }
  // reduce over the 16 lanes of each column group (lr bits)
#pragma unroll
  for (int r = 0; r < 4; ++r) {
    float s = dfull[r];
    s += __shfl_xor(s, 1, 64);
    s += __shfl_xor(s, 2, 64);
    s += __shfl_xor(s, 4, 64);
    s += __shfl_xor(s, 8, 64);
    dfull[r] = s;
  }
  if (lr == 0) {
#pragma unroll
    for (int r = 0; r < 4; ++r) dpart[(size_t)x * 64 + wave * 16 + g * 4 + r] = dfull[r];
  }
}

// ---------------- pcs accumulation (4-way j-split, disjoint columns) ----------------
__global__ __launch_bounds__(256) void k_pcs(const u16* __restrict__ qb, const u16* __restrict__ kb,
                                             const float* __restrict__ dpart,
                                             const float* __restrict__ idx_dec,
                                             float* __restrict__ pcs) {
  __shared__ u16 qs[64 * 64];
  __shared__ u16 ks[64 * 64];
  __shared__ float ppart[4][64];
  __shared__ float invd_s[64];
  const int tid = threadIdx.x, lane = tid & 63, wave = tid >> 6;
  const int lr = lane & 15, g = lane >> 4;
  const int x = blockIdx.x;
  const int sp = x & 3, c = (x >> 2) & 31, h = x >> 7;
  const int n = c + 1, base = n >> 2, rem = n & 3;
  const int lo = sp * base + (sp < rem ? sp : rem);
  const int cnt = base + (sp < rem ? 1 : 0);
  if (cnt == 0) return;  // uniform: whole block exits together

  stage64(qb + (size_t)(c * 64) * DD + h * DH, DD, qs, wave, lane);
  if (tid < 64) {
    size_t b0 = (size_t)((h * 32 + c) * 4) * 64 + tid;
    float s = dpart[b0] + dpart[b0 + 64] + dpart[b0 + 128] + dpart[b0 + 192];
    invd_s[tid] = 1.f / s;
  }
  __syncthreads();
  bf16x8 aq0 = frag64(qs, wave, 0, lane);
  bf16x8 aq1 = frag64(qs, wave, 1, lane);
  float coef[4];
#pragma unroll
  for (int r = 0; r < 4; ++r) {
    int row = wave * 16 + g * 4 + r;
    coef[r] = __expf(idx_dec[h * 64 + row]) * invd_s[row];
  }

  for (int t = 0; t < cnt; ++t) {
    int j = lo + t;
    __syncthreads();
    stage64(kb + (size_t)(j * 64) * DD + h * DH, DD, ks, wave, lane);
    __syncthreads();
#pragma unroll
    for (int f = 0; f < 4; ++f) {
      f32x4 z = {0.f, 0.f, 0.f, 0.f};
      z = mfma16(aq0, frag64(ks, f, 0, lane), z);
      z = mfma16(aq1, frag64(ks, f, 1, lane), z);
      float part = 0.f;
#pragma unroll
      for (int r = 0; r < 4; ++r) {
        float e = __expf(z[r] * 0.125f);
        if (j == c && (f * 16 + lr) > (wave * 16 + g * 4 + r)) e = 0.f;
        part += coef[r] * e;
      }
      part += __shfl_xor(part, 16, 64);
      part += __shfl_xor(part, 32, 64);
      if (g == 0) ppart[wave][f * 16 + lr] = part;
    }
    __syncthreads();
    if (tid < 64) {
      pcs[(size_t)(h * RSEG + c) * LL + j * 64 + tid] =
          ppart[0][tid] + ppart[1][tid] + ppart[2][tid] + ppart[3][tid];
    }
  }
}

// ---------------- terrace attention: out_t per (h,c), exactly <=2 tiles ----------------
__global__ __launch_bounds__(256) void k_terr(const u16* __restrict__ qb, const u16* __restrict__ kb,
                                              const u16* __restrict__ vT,
                                              float* __restrict__ out_t) {
  __shared__ u16 qs[64 * 64];
  __shared__ u16 ks[64 * 64];
  __shared__ u16 vt[64 * 64];
  __shared__ u16 pt[64 * 64];
  const int tid = threadIdx.x, lane = tid & 63, wave = tid >> 6;
  const int lr = lane & 15, g = lane >> 4;
  const int c = blockIdx.x & 31, h = blockIdx.x >> 5;

  stage64(qb + (size_t)(c * 64) * DD + h * DH, DD, qs, wave, lane);
  __syncthreads();
  bf16x8 aq0 = frag64(qs, wave, 0, lane);
  bf16x8 aq1 = frag64(qs, wave, 1, lane);

  f32x4 ot[4] = {};
  float dterr[4] = {0.f, 0.f, 0.f, 0.f};
  const int j0 = (c > 0) ? c - 1 : 0;
  for (int jj = j0; jj <= c; ++jj) {
    __syncthreads();
    stage64(kb + (size_t)(jj * 64) * DD + h * DH, DD, ks, wave, lane);
    stage64(vT + (size_t)(h * DH) * LL + jj * 64, LL, vt, wave, lane);
    __syncthreads();
#pragma unroll
    for (int f = 0; f < 4; ++f) {
      f32x4 z = {0.f, 0.f, 0.f, 0.f};
      z = mfma16(aq0, frag64(ks, f, 0, lane), z);
      z = mfma16(aq1, frag64(ks, f, 1, lane), z);
      float s4 = 0.f;
#pragma unroll
      for (int r = 0; r < 4; ++r) {
        float e = __expf(z[r] * 0.125f);
        if (jj == c && (f * 16 + lr) > (wave * 16 + g * 4 + r)) e = 0.f;
        int col = f * 16 + lr, rowb = g * 4 + r;
        *(u16*)((char*)pt + wave * 2048 + (col >> 3) * 256 + rowb * 16 + (col & 7) * 2) = f2bf(e);
        s4 += 0.f;  // placeholder for clarity; dterr handled below with shfl on per-r sums
        dterr[r] += 0.f;
        // accumulate per-row partial (sum over this f's 16 columns happens via shfl later)
        dterr[r] += e;
      }
      (void)s4;
    }
    __syncthreads();
#pragma unroll
    for (int t = 0; t < 2; ++t) {
      bf16x8 ap = frag64(pt, wave, t, lane);
#pragma unroll
      for (int f = 0; f < 4; ++f) ot[f] = mfma16(ap, frag64(vt, f, t, lane), ot[f]);
    }
  }
  // reduce dterr across the 16 lr lanes (covers all 64 columns over f accumulation)
  float invdt[4];
#pragma unroll
  for (int r = 0; r < 4; ++r) {
    float s = dterr[r];
    s += __shfl_xor(s, 1, 64);
    s += __shfl_xor(s, 2, 64);
    s += __shfl_xor(s, 4, 64);
    s += __shfl_xor(s, 8, 64);
    invdt[r] = 1.f / s;
  }
#pragma unroll
  for (int f = 0; f < 4; ++f)
#pragma unroll
    for (int r = 0; r < 4; ++r) {
      int srow = wave * 16 + g * 4 + r, e = f * 16 + lr;
      out_t[((size_t)(h * RSEG + c) * 64 + srow) * 64 + e] = ot[f][r] * invdt[r];
    }
}

// ---------------- segment scan (pcs tail gated to zero) ----------------
__global__ __launch_bounds__(256) void k_scan(const float* __restrict__ pcs,
                                              const float* __restrict__ mega_decays,
                                              float* __restrict__ w) {
  int idx = blockIdx.x * 256 + threadIdx.x;  // 16*2048
  int h = idx >> 11, m = idx & 2047;
  float mg = __expf(mega_decays[h] * 64.f);
  mg = fminf(fmaxf(mg, 0.f), 2.f);
  float carry = 0.f;
  for (int i = 0; i < RSEG; ++i) {
    size_t o = (size_t)(h * RSEG + i) * LL + m;
    w[o] = carry;
    float p = (m < (i + 1) * 64) ? pcs[o] : 0.f;
    carry = carry * mg + p;
  }
}

__global__ __launch_bounds__(256) void k_wsum(const float* __restrict__ w,
                                              float* __restrict__ inv_wsum) {
  __shared__ float red[256];
  int row = blockIdx.x;
  float s = 0.f;
  for (int m = threadIdx.x; m < LL; m += 256) s += w[(size_t)row * LL + m];
  red[threadIdx.x] = s;
  __syncthreads();
  for (int st = 128; st > 0; st >>= 1) {
    if (threadIdx.x < st) red[threadIdx.x] += red[threadIdx.x + st];
    __syncthreads();
  }
  if (threadIdx.x == 0) inv_wsum[row] = 1.f / (red[0] + 1e-5f);
}

// ---------------- kv state (2-way j-split, bf16 partials) ----------------
__global__ __launch_bounds__(256) void k_kv(const u16* __restrict__ kT, const u16* __restrict__ vT,
                                            const float* __restrict__ w,
                                            const float* __restrict__ inv_wsum,
                                            u16* __restrict__ kvp0, u16* __restrict__ kvp1) {
  __shared__ u16 kt[64 * 64];
  __shared__ u16 vt[64 * 64];
  __shared__ float wn[64];
  __shared__ float kvt[64 * 65];
  const int tid = threadIdx.x, lane = tid & 63, wave = tid >> 6;
  const int lr = lane & 15, g = lane >> 4;
  const int x = blockIdx.x;
  const int sp = x & 1, c = (x >> 1) & 31, h = x >> 6;
  const int n = c, base = n >> 1, rem = n & 1;
  const int lo = sp * base + (sp < rem ? sp : rem);
  const int cnt = base + (sp < rem ? 1 : 0);
  const float invw = inv_wsum[h * RSEG + c];
  f32x4 acc[4] = {};
  for (int t = 0; t < cnt; ++t) {
    int j = lo + t;
    __syncthreads();
    stage64(kT + (size_t)(h * DH) * LL + j * 64, LL, kt, wave, lane);
    stage64(vT + (size_t)(h * DH) * LL + j * 64, LL, vt, wave, lane);
    if (tid < 64) wn[tid] = w[(size_t)(h * RSEG + c) * LL + j * 64 + tid] * invw;
    __syncthreads();
#pragma unroll
    for (int t2 = 0; t2 < 2; ++t2) {
      bf16x8 raw = frag64(kt, wave, t2, lane);
      bf16x8 a;
      int m0 = t2 * 32 + g * 8;
#pragma unroll
      for (int i = 0; i < 8; ++i) a[i] = (__bf16)((float)raw[i] * wn[m0 + i]);
#pragma unroll
      for (int f = 0; f < 4; ++f) acc[f] = mfma16(a, frag64(vt, f, t2, lane), acc[f]);
    }
  }
  __syncthreads();
#pragma unroll
  for (int f = 0; f < 4; ++f)
#pragma unroll
    for (int r = 0; r < 4; ++r) kvt[(f * 16 + lr) * 65 + wave * 16 + g * 4 + r] = acc[f][r];
  __syncthreads();
  {
    int e = tid >> 2, d0 = (tid & 3) * 16;
    u16 tmp[16];
#pragma unroll
    for (int i = 0; i < 16; ++i) tmp[i] = f2bf(kvt[e * 65 + d0 + i]);
    u16* dst = (sp ? kvp1 : kvp0) + ((size_t)(h * 32 + c) * 64 + e) * 64 + d0;
    *(u16x8*)dst = *(const u16x8*)tmp;
    *(u16x8*)(dst + 8) = *(const u16x8*)(tmp + 8);
  }
}

// ---------------- out_lin + mix -> y (bf16) ----------------
__global__ __launch_bounds__(256) void k_outlin(const u16* __restrict__ qb,
                                                const u16* __restrict__ kvp0,
                                                const u16* __restrict__ kvp1,
                                                const float* __restrict__ out_t,
                                                const float* __restrict__ tmix,
                                                u16* __restrict__ yb) {
  const int tid = threadIdx.x, lane = tid & 63, wave = tid >> 6;
  const int lr = lane & 15, g = lane >> 4;
  const int c = blockIdx.x & 31, h = blockIdx.x >> 5;
  bf16x8 aq[2], bk[4][2];
#pragma unroll
  for (int t = 0; t < 2; ++t)
    aq[t] = *(const bf16x8*)(qb + (size_t)(c * 64 + wave * 16 + lr) * DD + h * DH + t * 32 + g * 8);
#pragma unroll
  for (int f = 0; f < 4; ++f)
#pragma unroll
    for (int t = 0; t < 2; ++t) {
      size_t off = ((size_t)(h * 32 + c) * 64 + f * 16 + lr) * 64 + t * 32 + g * 8;
      u16x8 p0 = *(const u16x8*)(kvp0 + off);
      u16x8 p1 = *(const u16x8*)(kvp1 + off);
      bf16x8 fr;
#pragma unroll
      for (int i = 0; i < 8; ++i) fr[i] = (__bf16)(bf2f(p0[i]) + bf2f(p1[i]));
      bk[f][t] = fr;
    }
  f32x4 ao[4] = {};
#pragma unroll
  for (int t = 0; t < 2; ++t)
#pragma unroll
    for (int f = 0; f < 4; ++f) ao[f] = mfma16(aq[t], bk[f][t], ao[f]);
  float tw[4];
#pragma unroll
  for (int r = 0; r < 4; ++r) tw[r] = 1.f / (1.f + __expf(-tmix[wave * 16 + g * 4 + r]));
#pragma unroll
  for (int f = 0; f < 4; ++f)
#pragma unroll
    for (int r = 0; r < 4; ++r) {
      int s = wave * 16 + g * 4 + r, e = f * 16 + lr;
      float otv = out_t[((size_t)(h * RSEG + c) * 64 + s) * 64 + e];
      float yv = tw[r] * otv + (1.f - tw[r]) * ao[f][r];
      yb[(size_t)(c * 64 + s) * DD + h * DH + e] = f2bf(yv);
    }
}

// ---------------- host launch ----------------
extern "C" void kernel_launch(void* const* d_in, const int* in_sizes, int n_in, void* d_out,
                              int out_size, void* d_ws, size_t ws_size, hipStream_t stream) {
  const float* hs = (const float*)d_in[0];
  const float* Wq = (const float*)d_in[1];
  const float* Wk = (const float*)d_in[2];
  const float* Wv = (const float*)d_in[3];
  const float* Wc = (const float*)d_in[4];
  const float* tmix = (const float*)d_in[5];
  const float* idx_dec = (const float*)d_in[6];
  const float* mega = (const float*)d_in[7];
  char* ws = (char*)d_ws;

  // workspace layout (bytes), total ~46 MB:
  u16* hs_bf = (u16*)(ws + 0);                 // 4 MB   [dead after QKV gemm]
  u16* wq_bf = (u16*)(ws + 4194304);           // 6 MB (Wq,Wk,Wv)  [dead after QKV gemm]
  u16* wc_bf = (u16*)(ws + 12582912);          // 2 MB   [until final gemm]
  u16* q_bf = (u16*)(ws + 14680064);           // 4 MB   [until k_outlin]
  u16* k_bf = q_bf + (size_t)LL * DD;          // 4 MB   [dead after k_pcs] -> kvp1
  u16* v_bf = q_bf + 2 * (size_t)LL * DD;      // 4 MB   [dead after transpose] -> kvp0
  u16* kT = (u16*)(ws + 27262976);             // 4 MB
  u16* vT = (u16*)(ws + 31457280);             // 4 MB
  float* pcs = (float*)(ws + 35651584);        // 4 MB
  float* wbuf = (float*)(ws + 39845888);       // 4 MB
  float* iws = (float*)(ws + 44040192);        // 2 KB
  float* dpart = (float*)(ws + 44044288);      // 512 KB
  float* out_t = (float*)(ws + 0);             // 8 MB (reuses hs_bf/Wq/Wk)
  u16* y_bf = (u16*)(ws + 8388608);            // 4 MB (reuses Wv copy + hole)
  u16* kvp1 = k_bf;                            // 4 MB bf16 partial
  u16* kvp0 = v_bf;                            // 4 MB bf16 partial

  k_castall<<<dim3(6291456 / 4 / 256), 256, 0, stream>>>(hs, Wq, Wk, Wv, Wc, hs_bf, wq_bf, wc_bf);

  k_gemm<false><<<dim3(DD / 128, LL / 128, 3), 256, 0, stream>>>(hs_bf, wq_bf, q_bf, nullptr);
  k_transpose<<<dim3(1024), 256, 0, stream>>>(k_bf, v_bf, kT, vT);

  k_den<<<dim3(2048), 256, 0, stream>>>(q_bf, k_bf, dpart);
  k_terr<<<dim3(512), 256, 0, stream>>>(q_bf, k_bf, vT, out_t);
  k_pcs<<<dim3(2048), 256, 0, stream>>>(q_bf, k_bf, dpart, idx_dec, pcs);

  k_scan<<<dim3(128), 256, 0, stream>>>(pcs, mega, wbuf);
  k_wsum<<<dim3(512), 256, 0, stream>>>(wbuf, iws);
  k_kv<<<dim3(1024), 256, 0, stream>>>(kT, vT, wbuf, iws, kvp0, kvp1);
  k_outlin<<<dim3(512), 256, 0, stream>>>(q_bf, kvp0, kvp1, out_t, tmix, y_bf);
  k_gemm<true><<<dim3(DD / 128, LL / 128, 1), 256, 0, stream>>>(y_bf, wc_bf, nullptr,
                                                                (float*)d_out);
  (void)in_sizes; (void)n_in; (void)out_size; (void)ws_size;
}

// Round 4
// 186.128 us; speedup vs baseline: 1.2089x; 1.0258x over previous
//
#include <hip/hip_runtime.h>
#include <cstdint>
#include <cstddef>

// Problem constants (b=1)
#define LL 2048     // sequence length
#define DD 1024     // model dim
#define NH 16       // heads
#define DH 64       // head dim
#define RSEG 32     // LL/64 chunks

using u16 = unsigned short;
typedef __attribute__((ext_vector_type(8))) __bf16 bf16x8;
typedef __attribute__((ext_vector_type(4))) float f32x4;
typedef __attribute__((ext_vector_type(8))) u16 u16x8;
typedef __attribute__((ext_vector_type(4))) u16 u16x4;
typedef __attribute__((ext_vector_type(4))) float f32x4v;

static __device__ __forceinline__ u16 f2bf(float f) {
  union { float f; unsigned u; } a; a.f = f;
  unsigned u = a.u;
  return (u16)((u + 0x7fffu + ((u >> 16) & 1u)) >> 16);
}
static __device__ __forceinline__ float bf2f(u16 x) {
  union { unsigned u; float f; } a; a.u = ((unsigned)x) << 16;
  return a.f;
}

static __device__ __forceinline__ f32x4 mfma16(bf16x8 a, bf16x8 b, f32x4 c) {
  return __builtin_amdgcn_mfma_f32_16x16x32_bf16(a, b, c, 0, 0, 0);
}

#define GLOAD_LDS16(gsrc, ldst)                                                        \
  __builtin_amdgcn_global_load_lds((const __attribute__((address_space(1))) void*)(gsrc), \
                                   (__attribute__((address_space(3))) void*)(ldst), 16, 0, 0)

// Stage a 64x64 bf16 tile from row-major global (row stride rs elems) into MFMA
// layout: byte = rb*2048 + kh*1024 + kg*256 + lr*16
static __device__ __forceinline__ void stage64(const u16* g, int rs, u16* lds, int wave, int lane) {
  int lr = lane & 15, kg = lane >> 4;
#pragma unroll
  for (int i = 0; i < 2; ++i) {
    int idx = wave * 2 + i;
    int rb = idx >> 1, kh = idx & 1;
    const u16* src = g + (size_t)(rb * 16 + lr) * rs + kh * 32 + kg * 8;
    GLOAD_LDS16(src, (char*)lds + idx * 1024);
  }
}

// Read one 16x32 A/B fragment (rows rb*16.., k = t*32..t*32+31)
static __device__ __forceinline__ bf16x8 frag64(const u16* lds, int rb, int t, int lane) {
  return *(const bf16x8*)((const char*)lds + rb * 2048 + t * 1024 + (lane >> 4) * 256 +
                          (lane & 15) * 16);
}

// ---------------- fused fp32 -> bf16 cast of all inputs ----------------
__global__ __launch_bounds__(256) void k_castall(const float* __restrict__ hs,
                                                 const float* __restrict__ Wq,
                                                 const float* __restrict__ Wk,
                                                 const float* __restrict__ Wv,
                                                 const float* __restrict__ Wc,
                                                 u16* __restrict__ hs_bf, u16* __restrict__ wq_bf,
                                                 u16* __restrict__ wc_bf) {
  int i = (blockIdx.x * 256 + threadIdx.x) * 4;  // over 6M elements
  const float* src;
  u16* dst;
  int off;
  if (i < 2097152) { src = hs; dst = hs_bf; off = i; }
  else if (i < 3145728) { src = Wq; dst = wq_bf; off = i - 2097152; }
  else if (i < 4194304) { src = Wk; dst = wq_bf + 1048576; off = i - 3145728; }
  else if (i < 5242880) { src = Wv; dst = wq_bf + 2097152; off = i - 4194304; }
  else { src = Wc; dst = wc_bf; off = i - 5242880; }
  f32x4v v = *(const f32x4v*)(src + off);
  u16x4 o;
#pragma unroll
  for (int t = 0; t < 4; ++t) o[t] = f2bf(v[t]);
  *(u16x4*)(dst + off) = o;
}

// ---------------- GEMM: C[M,N] = A[M,K] * B[N,K]^T, 2-phase double-buffered ----------------
template <int BM, int BN, bool WF32>
__global__ __launch_bounds__(256) void k_gemm(const u16* __restrict__ A, const u16* __restrict__ Ball,
                                              u16* __restrict__ Cb, float* __restrict__ Cf) {
  constexpr int FI = BM / 32, FJ = BN / 32;
  __shared__ u16 lA[2][BM * 64];
  __shared__ u16 lB[2][BN * 64];
  const int tid = threadIdx.x, lane = tid & 63, wave = tid >> 6;
  const int lr = lane & 15, kg = lane >> 4;
  const int wr = wave >> 1, wc = wave & 1;
  const u16* Bp = Ball + (size_t)blockIdx.z * (DD * DD);
  const int brow = blockIdx.y * BM, bcol = blockIdx.x * BN;
  f32x4 acc[FI][FJ] = {};

  auto stage = [&](int buf, int kt) {
#pragma unroll
    for (int i = 0; i < BM / 32; ++i) {
      int idx = wave * (BM / 32) + i;
      int rb = idx >> 1, kh = idx & 1;
      GLOAD_LDS16(A + (size_t)(brow + rb * 16 + lr) * DD + kt * 64 + kh * 32 + kg * 8,
                  (char*)(&lA[buf][0]) + idx * 1024);
    }
#pragma unroll
    for (int i = 0; i < BN / 32; ++i) {
      int idx = wave * (BN / 32) + i;
      int rb = idx >> 1, kh = idx & 1;
      GLOAD_LDS16(Bp + (size_t)(bcol + rb * 16 + lr) * DD + kt * 64 + kh * 32 + kg * 8,
                  (char*)(&lB[buf][0]) + idx * 1024);
    }
  };

  stage(0, 0);
  int cur = 0;
  for (int kt = 0; kt < DD / 64; ++kt) {
    __syncthreads();  // drains vmcnt(0): buf[cur] staged; buf[cur^1] free for reuse
    if (kt + 1 < DD / 64) stage(cur ^ 1, kt + 1);
    bf16x8 af[FI][2], bb[FJ][2];
#pragma unroll
    for (int f = 0; f < FI; ++f)
#pragma unroll
      for (int t = 0; t < 2; ++t)
        af[f][t] = *(const bf16x8*)((const char*)(&lA[cur][0]) + ((wr * FI + f) * 2 + t) * 1024 +
                                    kg * 256 + lr * 16);
#pragma unroll
    for (int f = 0; f < FJ; ++f)
#pragma unroll
      for (int t = 0; t < 2; ++t)
        bb[f][t] = *(const bf16x8*)((const char*)(&lB[cur][0]) + ((wc * FJ + f) * 2 + t) * 1024 +
                                    kg * 256 + lr * 16);
#pragma unroll
    for (int t = 0; t < 2; ++t)
#pragma unroll
      for (int i = 0; i < FI; ++i)
#pragma unroll
        for (int j = 0; j < FJ; ++j) acc[i][j] = mfma16(af[i][t], bb[j][t], acc[i][j]);
    cur ^= 1;
  }
  u16* Co = Cb + (size_t)blockIdx.z * ((size_t)LL * DD);
#pragma unroll
  for (int i = 0; i < FI; ++i)
#pragma unroll
    for (int j = 0; j < FJ; ++j)
#pragma unroll
      for (int r = 0; r < 4; ++r) {
        int row = brow + (wr * FI + i) * 16 + kg * 4 + r;
        int col = bcol + (wc * FJ + j) * 16 + lr;
        if constexpr (WF32)
          Cf[(size_t)row * DD + col] = acc[i][j][r];
        else
          Co[(size_t)row * DD + col] = f2bf(acc[i][j][r]);
      }
}

// ---------------- transpose k/v per head: [m][h*64+d] -> T[h][d][m] ----------------
__global__ __launch_bounds__(256) void k_transpose(const u16* __restrict__ kb,
                                                   const u16* __restrict__ vb, u16* __restrict__ kT,
                                                   u16* __restrict__ vT) {
  __shared__ u16 tile[64][72];
  int bid = blockIdx.x;
  int mt = bid >> 5, h = (bid >> 1) & 15, wch = bid & 1;
  const u16* src = wch ? vb : kb;
  u16* dst = wch ? vT : kT;
  int tid = threadIdx.x;
  int m = tid >> 3, d0 = (tid & 7) * 8;
#pragma unroll
  for (int i = 0; i < 2; ++i) {
    u16x8 v = *(const u16x8*)(src + (size_t)(mt * 64 + m + i * 32) * DD + h * DH + d0);
    *(u16x8*)&tile[m + i * 32][d0] = v;
  }
  __syncthreads();
  int d = tid >> 3, m0 = (tid & 7) * 8;
#pragma unroll
  for (int i = 0; i < 2; ++i) {
    u16 tmp[8];
#pragma unroll
    for (int t = 0; t < 8; ++t) tmp[t] = tile[m0 + t][d + i * 32];
    *(u16x8*)(dst + (size_t)(h * DH + d + i * 32) * LL + mt * 64 + m0) = *(const u16x8*)tmp;
  }
}

// ---------------- denominator partials: dpart[(h,c,sp)][row] ----------------
__global__ __launch_bounds__(256) void k_den(const u16* __restrict__ qb, const u16* __restrict__ kb,
                                             float* __restrict__ dpart) {
  __shared__ u16 qs[64 * 64];
  __shared__ u16 ks[64 * 64];
  const int tid = threadIdx.x, lane = tid & 63, wave = tid >> 6;
  const int lr = lane & 15, g = lane >> 4;
  const int x = blockIdx.x;
  const int sp = x & 3, c = (x >> 2) & 31, h = x >> 7;
  const int n = c + 1, base = n >> 2, rem = n & 3;
  const int lo = sp * base + (sp < rem ? sp : rem);
  const int cnt = base + (sp < rem ? 1 : 0);

  stage64(qb + (size_t)(c * 64) * DD + h * DH, DD, qs, wave, lane);
  __syncthreads();
  bf16x8 aq0 = frag64(qs, wave, 0, lane);
  bf16x8 aq1 = frag64(qs, wave, 1, lane);

  float dfull[4] = {0.f, 0.f, 0.f, 0.f};
  for (int t = 0; t < cnt; ++t) {
    int j = lo + t;
    __syncthreads();
    stage64(kb + (size_t)(j * 64) * DD + h * DH, DD, ks, wave, lane);
    __syncthreads();
#pragma unroll
    for (int f = 0; f < 4; ++f) {
      f32x4 z = {0.f, 0.f, 0.f, 0.f};
      z = mfma16(aq0, frag64(ks, f, 0, lane), z);
      z = mfma16(aq1, frag64(ks, f, 1, lane), z);
#pragma unroll
      for (int r = 0; r < 4; ++r) {
        float e = __expf(z[r] * 0.125f);
        if (j == c && (f * 16 + lr) > (wave * 16 + g * 4 + r)) e = 0.f;
        dfull[r] += e;
      }
    }
  }
#pragma unroll
  for (int r = 0; r < 4; ++r) {
    float s = dfull[r];
    s += __shfl_xor(s, 1, 64);
    s += __shfl_xor(s, 2, 64);
    s += __shfl_xor(s, 4, 64);
    s += __shfl_xor(s, 8, 64);
    dfull[r] = s;
  }
  if (lr == 0) {
#pragma unroll
    for (int r = 0; r < 4; ++r) dpart[(size_t)x * 64 + wave * 16 + g * 4 + r] = dfull[r];
  }
}

// ---------------- pcs accumulation (4-way j-split, disjoint columns) ----------------
__global__ __launch_bounds__(256) void k_pcs(const u16* __restrict__ qb, const u16* __restrict__ kb,
                                             const float* __restrict__ dpart,
                                             const float* __restrict__ idx_dec,
                                             float* __restrict__ pcs) {
  __shared__ u16 qs[64 * 64];
  __shared__ u16 ks[64 * 64];
  __shared__ float ppart[4][64];
  __shared__ float invd_s[64];
  const int tid = threadIdx.x, lane = tid & 63, wave = tid >> 6;
  const int lr = lane & 15, g = lane >> 4;
  const int x = blockIdx.x;
  const int sp = x & 3, c = (x >> 2) & 31, h = x >> 7;
  const int n = c + 1, base = n >> 2, rem = n & 3;
  const int lo = sp * base + (sp < rem ? sp : rem);
  const int cnt = base + (sp < rem ? 1 : 0);
  if (cnt == 0) return;  // uniform: whole block exits together

  stage64(qb + (size_t)(c * 64) * DD + h * DH, DD, qs, wave, lane);
  if (tid < 64) {
    size_t b0 = (size_t)((h * 32 + c) * 4) * 64 + tid;
    float s = dpart[b0] + dpart[b0 + 64] + dpart[b0 + 128] + dpart[b0 + 192];
    invd_s[tid] = 1.f / s;
  }
  __syncthreads();
  bf16x8 aq0 = frag64(qs, wave, 0, lane);
  bf16x8 aq1 = frag64(qs, wave, 1, lane);
  float coef[4];
#pragma unroll
  for (int r = 0; r < 4; ++r) {
    int row = wave * 16 + g * 4 + r;
    coef[r] = __expf(idx_dec[h * 64 + row]) * invd_s[row];
  }

  for (int t = 0; t < cnt; ++t) {
    int j = lo + t;
    __syncthreads();
    stage64(kb + (size_t)(j * 64) * DD + h * DH, DD, ks, wave, lane);
    __syncthreads();
#pragma unroll
    for (int f = 0; f < 4; ++f) {
      f32x4 z = {0.f, 0.f, 0.f, 0.f};
      z = mfma16(aq0, frag64(ks, f, 0, lane), z);
      z = mfma16(aq1, frag64(ks, f, 1, lane), z);
      float part = 0.f;
#pragma unroll
      for (int r = 0; r < 4; ++r) {
        float e = __expf(z[r] * 0.125f);
        if (j == c && (f * 16 + lr) > (wave * 16 + g * 4 + r)) e = 0.f;
        part += coef[r] * e;
      }
      part += __shfl_xor(part, 16, 64);
      part += __shfl_xor(part, 32, 64);
      if (g == 0) ppart[wave][f * 16 + lr] = part;
    }
    __syncthreads();
    if (tid < 64) {
      pcs[(size_t)(h * RSEG + c) * LL + j * 64 + tid] =
          ppart[0][tid] + ppart[1][tid] + ppart[2][tid] + ppart[3][tid];
    }
  }
}

// ---------------- terrace attention: out_t per (h,c), exactly <=2 tiles ----------------
__global__ __launch_bounds__(256) void k_terr(const u16* __restrict__ qb, const u16* __restrict__ kb,
                                              const u16* __restrict__ vT,
                                              float* __restrict__ out_t) {
  __shared__ u16 qs[64 * 64];
  __shared__ u16 ks[64 * 64];
  __shared__ u16 vt[64 * 64];
  __shared__ u16 pt[64 * 64];
  const int tid = threadIdx.x, lane = tid & 63, wave = tid >> 6;
  const int lr = lane & 15, g = lane >> 4;
  const int c = blockIdx.x & 31, h = blockIdx.x >> 5;

  stage64(qb + (size_t)(c * 64) * DD + h * DH, DD, qs, wave, lane);
  __syncthreads();
  bf16x8 aq0 = frag64(qs, wave, 0, lane);
  bf16x8 aq1 = frag64(qs, wave, 1, lane);

  f32x4 ot[4] = {};
  float dterr[4] = {0.f, 0.f, 0.f, 0.f};
  const int j0 = (c > 0) ? c - 1 : 0;
  for (int jj = j0; jj <= c; ++jj) {
    __syncthreads();
    stage64(kb + (size_t)(jj * 64) * DD + h * DH, DD, ks, wave, lane);
    stage64(vT + (size_t)(h * DH) * LL + jj * 64, LL, vt, wave, lane);
    __syncthreads();
#pragma unroll
    for (int f = 0; f < 4; ++f) {
      f32x4 z = {0.f, 0.f, 0.f, 0.f};
      z = mfma16(aq0, frag64(ks, f, 0, lane), z);
      z = mfma16(aq1, frag64(ks, f, 1, lane), z);
#pragma unroll
      for (int r = 0; r < 4; ++r) {
        float e = __expf(z[r] * 0.125f);
        if (jj == c && (f * 16 + lr) > (wave * 16 + g * 4 + r)) e = 0.f;
        int col = f * 16 + lr, rowb = g * 4 + r;
        *(u16*)((char*)pt + wave * 2048 + (col >> 3) * 256 + rowb * 16 + (col & 7) * 2) = f2bf(e);
        dterr[r] += e;
      }
    }
    __syncthreads();
#pragma unroll
    for (int t = 0; t < 2; ++t) {
      bf16x8 ap = frag64(pt, wave, t, lane);
#pragma unroll
      for (int f = 0; f < 4; ++f) ot[f] = mfma16(ap, frag64(vt, f, t, lane), ot[f]);
    }
  }
  float invdt[4];
#pragma unroll
  for (int r = 0; r < 4; ++r) {
    float s = dterr[r];
    s += __shfl_xor(s, 1, 64);
    s += __shfl_xor(s, 2, 64);
    s += __shfl_xor(s, 4, 64);
    s += __shfl_xor(s, 8, 64);
    invdt[r] = 1.f / s;
  }
#pragma unroll
  for (int f = 0; f < 4; ++f)
#pragma unroll
    for (int r = 0; r < 4; ++r) {
      int srow = wave * 16 + g * 4 + r, e = f * 16 + lr;
      out_t[((size_t)(h * RSEG + c) * 64 + srow) * 64 + e] = ot[f][r] * invdt[r];
    }
}

// ---------------- segment scan + fused per-block w row-sum partials ----------------
__global__ __launch_bounds__(256) void k_scan(const float* __restrict__ pcs,
                                              const float* __restrict__ mega_decays,
                                              float* __restrict__ w, float* __restrict__ wpart) {
  __shared__ float red[32][4];
  int idx = blockIdx.x * 256 + threadIdx.x;  // 16*2048; one block spans one h
  int h = idx >> 11, m = idx & 2047;
  int lane = threadIdx.x & 63, wave = threadIdx.x >> 6;
  float mg = __expf(mega_decays[h] * 64.f);
  mg = fminf(fmaxf(mg, 0.f), 2.f);
  float carry = 0.f;
  for (int i = 0; i < RSEG; ++i) {
    size_t o = (size_t)(h * RSEG + i) * LL + m;
    w[o] = carry;
    float s = carry;
    s += __shfl_xor(s, 1, 64);
    s += __shfl_xor(s, 2, 64);
    s += __shfl_xor(s, 4, 64);
    s += __shfl_xor(s, 8, 64);
    s += __shfl_xor(s, 16, 64);
    s += __shfl_xor(s, 32, 64);
    if (lane == 0) red[i][wave] = s;
    float p = (m < (i + 1) * 64) ? pcs[o] : 0.f;
    carry = carry * mg + p;
  }
  __syncthreads();
  if (threadIdx.x < 32) {
    float t = red[threadIdx.x][0] + red[threadIdx.x][1] + red[threadIdx.x][2] + red[threadIdx.x][3];
    wpart[blockIdx.x * 32 + threadIdx.x] = t;
  }
}

// ---------------- kv state (4-way j-split, bf16 partials) ----------------
// grid MUST be 4(sp) * 32(c) * 16(h) = 2048 blocks (h = x>>7).
__global__ __launch_bounds__(256) void k_kv(const u16* __restrict__ kT, const u16* __restrict__ vT,
                                            const float* __restrict__ w,
                                            const float* __restrict__ wpart,
                                            u16* __restrict__ kvp0, u16* __restrict__ kvp1,
                                            u16* __restrict__ kvp2, u16* __restrict__ kvp3) {
  __shared__ u16 kt[64 * 64];
  __shared__ u16 vt[64 * 64];
  __shared__ float wn[64];
  __shared__ float kvt[64 * 65];
  const int tid = threadIdx.x, lane = tid & 63, wave = tid >> 6;
  const int lr = lane & 15, g = lane >> 4;
  const int x = blockIdx.x;
  const int sp = x & 3, c = (x >> 2) & 31, h = x >> 7;
  const int n = c, base = n >> 2, rem = n & 3;
  const int lo = sp * base + (sp < rem ? sp : rem);
  const int cnt = base + (sp < rem ? 1 : 0);
  float ssum = 1e-5f;
#pragma unroll
  for (int b = 0; b < 8; ++b) ssum += wpart[(h * 8 + b) * 32 + c];
  const float invw = 1.f / ssum;
  f32x4 acc[4] = {};
  for (int t = 0; t < cnt; ++t) {
    int j = lo + t;
    __syncthreads();
    stage64(kT + (size_t)(h * DH) * LL + j * 64, LL, kt, wave, lane);
    stage64(vT + (size_t)(h * DH) * LL + j * 64, LL, vt, wave, lane);
    if (tid < 64) wn[tid] = w[(size_t)(h * RSEG + c) * LL + j * 64 + tid] * invw;
    __syncthreads();
#pragma unroll
    for (int t2 = 0; t2 < 2; ++t2) {
      bf16x8 raw = frag64(kt, wave, t2, lane);
      bf16x8 a;
      int m0 = t2 * 32 + g * 8;
#pragma unroll
      for (int i = 0; i < 8; ++i) a[i] = (__bf16)((float)raw[i] * wn[m0 + i]);
#pragma unroll
      for (int f = 0; f < 4; ++f) acc[f] = mfma16(a, frag64(vt, f, t2, lane), acc[f]);
    }
  }
  __syncthreads();
#pragma unroll
  for (int f = 0; f < 4; ++f)
#pragma unroll
    for (int r = 0; r < 4; ++r) kvt[(f * 16 + lr) * 65 + wave * 16 + g * 4 + r] = acc[f][r];
  __syncthreads();
  {
    int e = tid >> 2, d0 = (tid & 3) * 16;
    u16 tmp[16];
#pragma unroll
    for (int i = 0; i < 16; ++i) tmp[i] = f2bf(kvt[e * 65 + d0 + i]);
    u16* kvp = (sp == 0) ? kvp0 : (sp == 1) ? kvp1 : (sp == 2) ? kvp2 : kvp3;
    u16* dst = kvp + ((size_t)(h * 32 + c) * 64 + e) * 64 + d0;
    *(u16x8*)dst = *(const u16x8*)tmp;
    *(u16x8*)(dst + 8) = *(const u16x8*)(tmp + 8);
  }
}

// ---------------- out_lin + mix -> y (bf16) ----------------
__global__ __launch_bounds__(256) void k_outlin(const u16* __restrict__ qb,
                                                const u16* __restrict__ kvp0,
                                                const u16* __restrict__ kvp1,
                                                const u16* __restrict__ kvp2,
                                                const u16* __restrict__ kvp3,
                                                const float* __restrict__ out_t,
                                                const float* __restrict__ tmix,
                                                u16* __restrict__ yb) {
  const int tid = threadIdx.x, lane = tid & 63, wave = tid >> 6;
  const int lr = lane & 15, g = lane >> 4;
  const int c = blockIdx.x & 31, h = blockIdx.x >> 5;
  bf16x8 aq[2], bk[4][2];
#pragma unroll
  for (int t = 0; t < 2; ++t)
    aq[t] = *(const bf16x8*)(qb + (size_t)(c * 64 + wave * 16 + lr) * DD + h * DH + t * 32 + g * 8);
#pragma unroll
  for (int f = 0; f < 4; ++f)
#pragma unroll
    for (int t = 0; t < 2; ++t) {
      size_t off = ((size_t)(h * 32 + c) * 64 + f * 16 + lr) * 64 + t * 32 + g * 8;
      u16x8 p0 = *(const u16x8*)(kvp0 + off);
      u16x8 p1 = *(const u16x8*)(kvp1 + off);
      u16x8 p2 = *(const u16x8*)(kvp2 + off);
      u16x8 p3 = *(const u16x8*)(kvp3 + off);
      bf16x8 fr;
#pragma unroll
      for (int i = 0; i < 8; ++i)
        fr[i] = (__bf16)((bf2f(p0[i]) + bf2f(p1[i])) + (bf2f(p2[i]) + bf2f(p3[i])));
      bk[f][t] = fr;
    }
  f32x4 ao[4] = {};
#pragma unroll
  for (int t = 0; t < 2; ++t)
#pragma unroll
    for (int f = 0; f < 4; ++f) ao[f] = mfma16(aq[t], bk[f][t], ao[f]);
  float tw[4];
#pragma unroll
  for (int r = 0; r < 4; ++r) tw[r] = 1.f / (1.f + __expf(-tmix[wave * 16 + g * 4 + r]));
#pragma unroll
  for (int f = 0; f < 4; ++f)
#pragma unroll
    for (int r = 0; r < 4; ++r) {
      int s = wave * 16 + g * 4 + r, e = f * 16 + lr;
      float otv = out_t[((size_t)(h * RSEG + c) * 64 + s) * 64 + e];
      float yv = tw[r] * otv + (1.f - tw[r]) * ao[f][r];
      yb[(size_t)(c * 64 + s) * DD + h * DH + e] = f2bf(yv);
    }
}

// ---------------- host launch ----------------
extern "C" void kernel_launch(void* const* d_in, const int* in_sizes, int n_in, void* d_out,
                              int out_size, void* d_ws, size_t ws_size, hipStream_t stream) {
  const float* hs = (const float*)d_in[0];
  const float* Wq = (const float*)d_in[1];
  const float* Wk = (const float*)d_in[2];
  const float* Wv = (const float*)d_in[3];
  const float* Wc = (const float*)d_in[4];
  const float* tmix = (const float*)d_in[5];
  const float* idx_dec = (const float*)d_in[6];
  const float* mega = (const float*)d_in[7];
  char* ws = (char*)d_ws;

  // workspace layout (bytes), max offset 48234496 (round-1 proven footprint):
  u16* hs_bf = (u16*)(ws + 0);                 // 4 MB   [dead after QKV gemm]
  u16* wq_bf = (u16*)(ws + 4194304);           // 6 MB   [dead after QKV gemm]
  float* dpart = (float*)(ws + 10485760);      // 512 KB [k_den -> k_pcs; dead before k_outlin's y_bf write]
  float* wpart = (float*)(ws + 11010048);      // 16 KB  [k_scan -> k_kv; dead before k_outlin's y_bf write]
  u16* wc_bf = (u16*)(ws + 12582912);          // 2 MB   [until final gemm]
  u16* q_bf = (u16*)(ws + 14680064);           // 4 MB   [until k_outlin]
  u16* k_bf = q_bf + (size_t)LL * DD;          // 4 MB   [dead after k_pcs] -> kvp1
  u16* v_bf = q_bf + 2 * (size_t)LL * DD;      // 4 MB   [dead after transpose] -> kvp0
  u16* kT = (u16*)(ws + 27262976);             // 4 MB
  u16* vT = (u16*)(ws + 31457280);             // 4 MB
  float* pcs = (float*)(ws + 35651584);        // 4 MB   [dead after k_scan] -> kvp2
  float* wbuf = (float*)(ws + 39845888);       // 4 MB
  u16* kvp3 = (u16*)(ws + 44040192);           // 4 MB
  float* out_t = (float*)(ws + 0);             // 8 MB (reuses hs_bf + Wq/Wk region)
  u16* y_bf = (u16*)(ws + 8388608);            // 4 MB (reuses Wv + hole; written by k_outlin)
  u16* kvp0 = v_bf;
  u16* kvp1 = k_bf;
  u16* kvp2 = (u16*)pcs;

  k_castall<<<dim3(6291456 / 4 / 256), 256, 0, stream>>>(hs, Wq, Wk, Wv, Wc, hs_bf, wq_bf, wc_bf);

  k_gemm<128, 128, false><<<dim3(DD / 128, LL / 128, 3), 256, 0, stream>>>(hs_bf, wq_bf, q_bf,
                                                                           nullptr);
  k_transpose<<<dim3(1024), 256, 0, stream>>>(k_bf, v_bf, kT, vT);

  k_den<<<dim3(2048), 256, 0, stream>>>(q_bf, k_bf, dpart);
  k_terr<<<dim3(512), 256, 0, stream>>>(q_bf, k_bf, vT, out_t);
  k_pcs<<<dim3(2048), 256, 0, stream>>>(q_bf, k_bf, dpart, idx_dec, pcs);

  k_scan<<<dim3(128), 256, 0, stream>>>(pcs, mega, wbuf, wpart);
  k_kv<<<dim3(2048), 256, 0, stream>>>(kT, vT, wbuf, wpart, kvp0, kvp1, kvp2, kvp3);  // 4*32*16
  k_outlin<<<dim3(512), 256, 0, stream>>>(q_bf, kvp0, kvp1, kvp2, kvp3, out_t, tmix, y_bf);
  k_gemm<64, 128, true><<<dim3(DD / 128, LL / 64, 1), 256, 0, stream>>>(y_bf, wc_bf, nullptr,
                                                                        (float*)d_out);
  (void)in_sizes; (void)n_in; (void)out_size; (void)ws_size;
}

// Round 5
// 178.092 us; speedup vs baseline: 1.2635x; 1.0451x over previous
//
#include <hip/hip_runtime.h>
#include <cstdint>
#include <cstddef>

// Problem constants (b=1)
#define LL 2048     // sequence length
#define DD 1024     // model dim
#define NH 16       // heads
#define DH 64       // head dim
#define RSEG 32     // LL/64 chunks

using u16 = unsigned short;
typedef __attribute__((ext_vector_type(8))) __bf16 bf16x8;
typedef __attribute__((ext_vector_type(4))) float f32x4;
typedef __attribute__((ext_vector_type(8))) u16 u16x8;
typedef __attribute__((ext_vector_type(4))) u16 u16x4;
typedef __attribute__((ext_vector_type(4))) float f32x4v;

static __device__ __forceinline__ u16 f2bf(float f) {
  union { float f; unsigned u; } a; a.f = f;
  unsigned u = a.u;
  return (u16)((u + 0x7fffu + ((u >> 16) & 1u)) >> 16);
}
static __device__ __forceinline__ float bf2f(u16 x) {
  union { unsigned u; float f; } a; a.u = ((unsigned)x) << 16;
  return a.f;
}

static __device__ __forceinline__ f32x4 mfma16(bf16x8 a, bf16x8 b, f32x4 c) {
  return __builtin_amdgcn_mfma_f32_16x16x32_bf16(a, b, c, 0, 0, 0);
}

#define GLOAD_LDS16(gsrc, ldst)                                                        \
  __builtin_amdgcn_global_load_lds((const __attribute__((address_space(1))) void*)(gsrc), \
                                   (__attribute__((address_space(3))) void*)(ldst), 16, 0, 0)

// Stage a 64x64 bf16 tile from row-major global (row stride rs elems) into MFMA
// layout: byte = rb*2048 + kh*1024 + kg*256 + lr*16
static __device__ __forceinline__ void stage64(const u16* g, int rs, u16* lds, int wave, int lane) {
  int lr = lane & 15, kg = lane >> 4;
#pragma unroll
  for (int i = 0; i < 2; ++i) {
    int idx = wave * 2 + i;
    int rb = idx >> 1, kh = idx & 1;
    const u16* src = g + (size_t)(rb * 16 + lr) * rs + kh * 32 + kg * 8;
    GLOAD_LDS16(src, (char*)lds + idx * 1024);
  }
}

// Read one 16x32 A/B fragment (rows rb*16.., k = t*32..t*32+31)
static __device__ __forceinline__ bf16x8 frag64(const u16* lds, int rb, int t, int lane) {
  return *(const bf16x8*)((const char*)lds + rb * 2048 + t * 1024 + (lane >> 4) * 256 +
                          (lane & 15) * 16);
}

// ---------------- fused fp32 -> bf16 cast of all inputs ----------------
__global__ __launch_bounds__(256) void k_castall(const float* __restrict__ hs,
                                                 const float* __restrict__ Wq,
                                                 const float* __restrict__ Wk,
                                                 const float* __restrict__ Wv,
                                                 const float* __restrict__ Wc,
                                                 u16* __restrict__ hs_bf, u16* __restrict__ wq_bf,
                                                 u16* __restrict__ wc_bf) {
  int i = (blockIdx.x * 256 + threadIdx.x) * 4;  // over 6M elements
  const float* src;
  u16* dst;
  int off;
  if (i < 2097152) { src = hs; dst = hs_bf; off = i; }
  else if (i < 3145728) { src = Wq; dst = wq_bf; off = i - 2097152; }
  else if (i < 4194304) { src = Wk; dst = wq_bf + 1048576; off = i - 3145728; }
  else if (i < 5242880) { src = Wv; dst = wq_bf + 2097152; off = i - 4194304; }
  else { src = Wc; dst = wc_bf; off = i - 5242880; }
  f32x4v v = *(const f32x4v*)(src + off);
  u16x4 o;
#pragma unroll
  for (int t = 0; t < 4; ++t) o[t] = f2bf(v[t]);
  *(u16x4*)(dst + off) = o;
}

// ---------------- GEMM: C[M,N] = A[M,K] * B[N,K]^T, dbuf BK=32 (32KB LDS) ----------------
template <int BM, int BN, bool WF32>
__global__ __launch_bounds__(256) void k_gemm(const u16* __restrict__ A, const u16* __restrict__ Ball,
                                              u16* __restrict__ Cb, float* __restrict__ Cf) {
  constexpr int FI = BM / 32, FJ = BN / 32;
  __shared__ u16 lA[2][BM * 32];
  __shared__ u16 lB[2][BN * 32];
  const int tid = threadIdx.x, lane = tid & 63, wave = tid >> 6;
  const int lr = lane & 15, kg = lane >> 4;
  const int wr = wave >> 1, wc = wave & 1;
  const u16* Bp = Ball + (size_t)blockIdx.z * (DD * DD);
  const int brow = blockIdx.y * BM, bcol = blockIdx.x * BN;
  f32x4 acc[FI][FJ] = {};

  auto stage = [&](int buf, int kt) {
#pragma unroll
    for (int i = 0; i < BM / 64; ++i) {
      int rb = wave * (BM / 64) + i;
      GLOAD_LDS16(A + (size_t)(brow + rb * 16 + lr) * DD + kt * 32 + kg * 8,
                  (char*)(&lA[buf][0]) + rb * 1024);
    }
#pragma unroll
    for (int i = 0; i < BN / 64; ++i) {
      int rb = wave * (BN / 64) + i;
      GLOAD_LDS16(Bp + (size_t)(bcol + rb * 16 + lr) * DD + kt * 32 + kg * 8,
                  (char*)(&lB[buf][0]) + rb * 1024);
    }
  };

  stage(0, 0);
  int cur = 0;
  for (int kt = 0; kt < DD / 32; ++kt) {
    __syncthreads();  // drains vmcnt(0): buf[cur] staged; buf[cur^1] free for reuse
    if (kt + 1 < DD / 32) stage(cur ^ 1, kt + 1);
    bf16x8 af[FI], bb[FJ];
#pragma unroll
    for (int f = 0; f < FI; ++f)
      af[f] = *(const bf16x8*)((const char*)(&lA[cur][0]) + (wr * FI + f) * 1024 + kg * 256 +
                               lr * 16);
#pragma unroll
    for (int f = 0; f < FJ; ++f)
      bb[f] = *(const bf16x8*)((const char*)(&lB[cur][0]) + (wc * FJ + f) * 1024 + kg * 256 +
                               lr * 16);
#pragma unroll
    for (int i = 0; i < FI; ++i)
#pragma unroll
      for (int j = 0; j < FJ; ++j) acc[i][j] = mfma16(af[i], bb[j], acc[i][j]);
    cur ^= 1;
  }
  u16* Co = Cb + (size_t)blockIdx.z * ((size_t)LL * DD);
#pragma unroll
  for (int i = 0; i < FI; ++i)
#pragma unroll
    for (int j = 0; j < FJ; ++j)
#pragma unroll
      for (int r = 0; r < 4; ++r) {
        int row = brow + (wr * FI + i) * 16 + kg * 4 + r;
        int col = bcol + (wc * FJ + j) * 16 + lr;
        if constexpr (WF32)
          Cf[(size_t)row * DD + col] = acc[i][j][r];
        else
          Co[(size_t)row * DD + col] = f2bf(acc[i][j][r]);
      }
}

// ---------------- transpose (blocks 0..1023) + den partials (blocks 1024..3071) ----------------
__global__ __launch_bounds__(256) void k_tden(const u16* __restrict__ kb, const u16* __restrict__ vb,
                                              u16* __restrict__ kT, u16* __restrict__ vT,
                                              const u16* __restrict__ qb,
                                              float* __restrict__ dpart) {
  __shared__ u16 smem[8192];
  const int tid = threadIdx.x;
  const int x = blockIdx.x;
  if (x < 1024) {
    // transpose k/v per head: [m][h*64+d] -> T[h][d][m]
    u16(*tile)[72] = (u16(*)[72])smem;  // 64*72 = 4608 <= 8192
    int mt = x >> 5, h = (x >> 1) & 15, wch = x & 1;
    const u16* src = wch ? vb : kb;
    u16* dst = wch ? vT : kT;
    int m = tid >> 3, d0 = (tid & 7) * 8;
#pragma unroll
    for (int i = 0; i < 2; ++i) {
      u16x8 v = *(const u16x8*)(src + (size_t)(mt * 64 + m + i * 32) * DD + h * DH + d0);
      *(u16x8*)&tile[m + i * 32][d0] = v;
    }
    __syncthreads();
    int d = tid >> 3, m0 = (tid & 7) * 8;
#pragma unroll
    for (int i = 0; i < 2; ++i) {
      u16 tmp[8];
#pragma unroll
      for (int t = 0; t < 8; ++t) tmp[t] = tile[m0 + t][d + i * 32];
      *(u16x8*)(dst + (size_t)(h * DH + d + i * 32) * LL + mt * 64 + m0) = *(const u16x8*)tmp;
    }
  } else {
    // den: softmax denominator partials, 4-way j-split
    u16* qs = smem;
    u16* ks = smem + 4096;
    const int lane = tid & 63, wave = tid >> 6;
    const int lr = lane & 15, g = lane >> 4;
    const int xx = x - 1024;
    const int sp = xx & 3, c = (xx >> 2) & 31, h = xx >> 7;
    const int n = c + 1, base = n >> 2, rem = n & 3;
    const int lo = sp * base + (sp < rem ? sp : rem);
    const int cnt = base + (sp < rem ? 1 : 0);

    stage64(qb + (size_t)(c * 64) * DD + h * DH, DD, qs, wave, lane);
    __syncthreads();
    bf16x8 aq0 = frag64(qs, wave, 0, lane);
    bf16x8 aq1 = frag64(qs, wave, 1, lane);

    float dfull[4] = {0.f, 0.f, 0.f, 0.f};
    for (int t = 0; t < cnt; ++t) {
      int j = lo + t;
      __syncthreads();
      stage64(kb + (size_t)(j * 64) * DD + h * DH, DD, ks, wave, lane);
      __syncthreads();
#pragma unroll
      for (int f = 0; f < 4; ++f) {
        f32x4 z = {0.f, 0.f, 0.f, 0.f};
        z = mfma16(aq0, frag64(ks, f, 0, lane), z);
        z = mfma16(aq1, frag64(ks, f, 1, lane), z);
#pragma unroll
        for (int r = 0; r < 4; ++r) {
          float e = __expf(z[r] * 0.125f);
          if (j == c && (f * 16 + lr) > (wave * 16 + g * 4 + r)) e = 0.f;
          dfull[r] += e;
        }
      }
    }
#pragma unroll
    for (int r = 0; r < 4; ++r) {
      float s = dfull[r];
      s += __shfl_xor(s, 1, 64);
      s += __shfl_xor(s, 2, 64);
      s += __shfl_xor(s, 4, 64);
      s += __shfl_xor(s, 8, 64);
      dfull[r] = s;
    }
    if (lr == 0) {
#pragma unroll
      for (int r = 0; r < 4; ++r) dpart[(size_t)xx * 64 + wave * 16 + g * 4 + r] = dfull[r];
    }
  }
}

// ---------------- pcs (blocks 0..2047) + terrace attention (blocks 2048..2559) ----------------
__global__ __launch_bounds__(256) void k_tpcs(const u16* __restrict__ qb, const u16* __restrict__ kb,
                                              const u16* __restrict__ vT,
                                              const float* __restrict__ dpart,
                                              const float* __restrict__ idx_dec,
                                              float* __restrict__ pcs, float* __restrict__ out_t) {
  __shared__ u16 smem[16384];
  __shared__ float fsm[320];
  const int tid = threadIdx.x, lane = tid & 63, wave = tid >> 6;
  const int lr = lane & 15, g = lane >> 4;
  const int x = blockIdx.x;
  if (x < 2048) {
    // pcs accumulation (4-way j-split, disjoint columns)
    u16* qs = smem;
    u16* ks = smem + 4096;
    float* ppart = fsm;          // [4][64]
    float* invd_s = fsm + 256;   // [64]
    const int sp = x & 3, c = (x >> 2) & 31, h = x >> 7;
    const int n = c + 1, base = n >> 2, rem = n & 3;
    const int lo = sp * base + (sp < rem ? sp : rem);
    const int cnt = base + (sp < rem ? 1 : 0);
    if (cnt == 0) return;  // uniform: whole block exits together

    stage64(qb + (size_t)(c * 64) * DD + h * DH, DD, qs, wave, lane);
    if (tid < 64) {
      size_t b0 = (size_t)((h * 32 + c) * 4) * 64 + tid;
      float s = dpart[b0] + dpart[b0 + 64] + dpart[b0 + 128] + dpart[b0 + 192];
      invd_s[tid] = 1.f / s;
    }
    __syncthreads();
    bf16x8 aq0 = frag64(qs, wave, 0, lane);
    bf16x8 aq1 = frag64(qs, wave, 1, lane);
    float coef[4];
#pragma unroll
    for (int r = 0; r < 4; ++r) {
      int row = wave * 16 + g * 4 + r;
      coef[r] = __expf(idx_dec[h * 64 + row]) * invd_s[row];
    }

    for (int t = 0; t < cnt; ++t) {
      int j = lo + t;
      __syncthreads();
      stage64(kb + (size_t)(j * 64) * DD + h * DH, DD, ks, wave, lane);
      __syncthreads();
#pragma unroll
      for (int f = 0; f < 4; ++f) {
        f32x4 z = {0.f, 0.f, 0.f, 0.f};
        z = mfma16(aq0, frag64(ks, f, 0, lane), z);
        z = mfma16(aq1, frag64(ks, f, 1, lane), z);
        float part = 0.f;
#pragma unroll
        for (int r = 0; r < 4; ++r) {
          float e = __expf(z[r] * 0.125f);
          if (j == c && (f * 16 + lr) > (wave * 16 + g * 4 + r)) e = 0.f;
          part += coef[r] * e;
        }
        part += __shfl_xor(part, 16, 64);
        part += __shfl_xor(part, 32, 64);
        if (g == 0) ppart[wave * 64 + f * 16 + lr] = part;
      }
      __syncthreads();
      if (tid < 64) {
        pcs[(size_t)(h * RSEG + c) * LL + j * 64 + tid] =
            ppart[tid] + ppart[64 + tid] + ppart[128 + tid] + ppart[192 + tid];
      }
    }
  } else {
    // terrace attention: out_t per (h,c), exactly <=2 tiles
    u16* qs = smem;
    u16* ks = smem + 4096;
    u16* vt = smem + 8192;
    u16* pt = smem + 12288;
    const int xx = x - 2048;
    const int c = xx & 31, h = xx >> 5;

    stage64(qb + (size_t)(c * 64) * DD + h * DH, DD, qs, wave, lane);
    __syncthreads();
    bf16x8 aq0 = frag64(qs, wave, 0, lane);
    bf16x8 aq1 = frag64(qs, wave, 1, lane);

    f32x4 ot[4] = {};
    float dterr[4] = {0.f, 0.f, 0.f, 0.f};
    const int j0 = (c > 0) ? c - 1 : 0;
    for (int jj = j0; jj <= c; ++jj) {
      __syncthreads();
      stage64(kb + (size_t)(jj * 64) * DD + h * DH, DD, ks, wave, lane);
      stage64(vT + (size_t)(h * DH) * LL + jj * 64, LL, vt, wave, lane);
      __syncthreads();
#pragma unroll
      for (int f = 0; f < 4; ++f) {
        f32x4 z = {0.f, 0.f, 0.f, 0.f};
        z = mfma16(aq0, frag64(ks, f, 0, lane), z);
        z = mfma16(aq1, frag64(ks, f, 1, lane), z);
#pragma unroll
        for (int r = 0; r < 4; ++r) {
          float e = __expf(z[r] * 0.125f);
          if (jj == c && (f * 16 + lr) > (wave * 16 + g * 4 + r)) e = 0.f;
          int col = f * 16 + lr, rowb = g * 4 + r;
          *(u16*)((char*)pt + wave * 2048 + (col >> 3) * 256 + rowb * 16 + (col & 7) * 2) = f2bf(e);
          dterr[r] += e;
        }
      }
      __syncthreads();
#pragma unroll
      for (int t = 0; t < 2; ++t) {
        bf16x8 ap = frag64(pt, wave, t, lane);
#pragma unroll
        for (int f = 0; f < 4; ++f) ot[f] = mfma16(ap, frag64(vt, f, t, lane), ot[f]);
      }
    }
    float invdt[4];
#pragma unroll
    for (int r = 0; r < 4; ++r) {
      float s = dterr[r];
      s += __shfl_xor(s, 1, 64);
      s += __shfl_xor(s, 2, 64);
      s += __shfl_xor(s, 4, 64);
      s += __shfl_xor(s, 8, 64);
      invdt[r] = 1.f / s;
    }
#pragma unroll
    for (int f = 0; f < 4; ++f)
#pragma unroll
      for (int r = 0; r < 4; ++r) {
        int srow = wave * 16 + g * 4 + r, e = f * 16 + lr;
        out_t[((size_t)(h * RSEG + c) * 64 + srow) * 64 + e] = ot[f][r] * invdt[r];
      }
  }
}

// ---------------- segment scan + fused per-block w row-sum partials ----------------
// 256 blocks x 128 threads: block = (h, m-chunk of 128)
__global__ __launch_bounds__(128) void k_scan(const float* __restrict__ pcs,
                                              const float* __restrict__ mega_decays,
                                              float* __restrict__ w, float* __restrict__ wpart) {
  __shared__ float red[32][2];
  int bid = blockIdx.x;
  int h = bid >> 4, m = (bid & 15) * 128 + threadIdx.x;
  int lane = threadIdx.x & 63, wave = threadIdx.x >> 6;
  float mg = __expf(mega_decays[h] * 64.f);
  mg = fminf(fmaxf(mg, 0.f), 2.f);
  float carry = 0.f;
  for (int i = 0; i < RSEG; ++i) {
    size_t o = (size_t)(h * RSEG + i) * LL + m;
    w[o] = carry;
    float s = carry;
    s += __shfl_xor(s, 1, 64);
    s += __shfl_xor(s, 2, 64);
    s += __shfl_xor(s, 4, 64);
    s += __shfl_xor(s, 8, 64);
    s += __shfl_xor(s, 16, 64);
    s += __shfl_xor(s, 32, 64);
    if (lane == 0) red[i][wave] = s;
    float p = (m < (i + 1) * 64) ? pcs[o] : 0.f;
    carry = carry * mg + p;
  }
  __syncthreads();
  if (threadIdx.x < 32) {
    wpart[bid * 32 + threadIdx.x] = red[threadIdx.x][0] + red[threadIdx.x][1];
  }
}

// ---------------- kv state (4-way j-split, bf16 partials) ----------------
// grid MUST be 4(sp) * 32(c) * 16(h) = 2048 blocks (h = x>>7).
__global__ __launch_bounds__(256) void k_kv(const u16* __restrict__ kT, const u16* __restrict__ vT,
                                            const float* __restrict__ w,
                                            const float* __restrict__ wpart,
                                            u16* __restrict__ kvp0, u16* __restrict__ kvp1,
                                            u16* __restrict__ kvp2, u16* __restrict__ kvp3) {
  __shared__ u16 kt[64 * 64];
  __shared__ u16 vt[64 * 64];
  __shared__ float wn[64];
  __shared__ float kvt[64 * 65];
  const int tid = threadIdx.x, lane = tid & 63, wave = tid >> 6;
  const int lr = lane & 15, g = lane >> 4;
  const int x = blockIdx.x;
  const int sp = x & 3, c = (x >> 2) & 31, h = x >> 7;
  const int n = c, base = n >> 2, rem = n & 3;
  const int lo = sp * base + (sp < rem ? sp : rem);
  const int cnt = base + (sp < rem ? 1 : 0);
  float ssum = 1e-5f;
#pragma unroll
  for (int b = 0; b < 16; ++b) ssum += wpart[(h * 16 + b) * 32 + c];
  const float invw = 1.f / ssum;
  f32x4 acc[4] = {};
  for (int t = 0; t < cnt; ++t) {
    int j = lo + t;
    __syncthreads();
    stage64(kT + (size_t)(h * DH) * LL + j * 64, LL, kt, wave, lane);
    stage64(vT + (size_t)(h * DH) * LL + j * 64, LL, vt, wave, lane);
    if (tid < 64) wn[tid] = w[(size_t)(h * RSEG + c) * LL + j * 64 + tid] * invw;
    __syncthreads();
#pragma unroll
    for (int t2 = 0; t2 < 2; ++t2) {
      bf16x8 raw = frag64(kt, wave, t2, lane);
      bf16x8 a;
      int m0 = t2 * 32 + g * 8;
#pragma unroll
      for (int i = 0; i < 8; ++i) a[i] = (__bf16)((float)raw[i] * wn[m0 + i]);
#pragma unroll
      for (int f = 0; f < 4; ++f) acc[f] = mfma16(a, frag64(vt, f, t2, lane), acc[f]);
    }
  }
  __syncthreads();
#pragma unroll
  for (int f = 0; f < 4; ++f)
#pragma unroll
    for (int r = 0; r < 4; ++r) kvt[(f * 16 + lr) * 65 + wave * 16 + g * 4 + r] = acc[f][r];
  __syncthreads();
  {
    int e = tid >> 2, d0 = (tid & 3) * 16;
    u16 tmp[16];
#pragma unroll
    for (int i = 0; i < 16; ++i) tmp[i] = f2bf(kvt[e * 65 + d0 + i]);
    u16* kvp = (sp == 0) ? kvp0 : (sp == 1) ? kvp1 : (sp == 2) ? kvp2 : kvp3;
    u16* dst = kvp + ((size_t)(h * 32 + c) * 64 + e) * 64 + d0;
    *(u16x8*)dst = *(const u16x8*)tmp;
    *(u16x8*)(dst + 8) = *(const u16x8*)(tmp + 8);
  }
}

// ---------------- out_lin + mix -> y (bf16) ----------------
__global__ __launch_bounds__(256) void k_outlin(const u16* __restrict__ qb,
                                                const u16* __restrict__ kvp0,
                                                const u16* __restrict__ kvp1,
                                                const u16* __restrict__ kvp2,
                                                const u16* __restrict__ kvp3,
                                                const float* __restrict__ out_t,
                                                const float* __restrict__ tmix,
                                                u16* __restrict__ yb) {
  const int tid = threadIdx.x, lane = tid & 63, wave = tid >> 6;
  const int lr = lane & 15, g = lane >> 4;
  const int c = blockIdx.x & 31, h = blockIdx.x >> 5;
  bf16x8 aq[2], bk[4][2];
#pragma unroll
  for (int t = 0; t < 2; ++t)
    aq[t] = *(const bf16x8*)(qb + (size_t)(c * 64 + wave * 16 + lr) * DD + h * DH + t * 32 + g * 8);
#pragma unroll
  for (int f = 0; f < 4; ++f)
#pragma unroll
    for (int t = 0; t < 2; ++t) {
      size_t off = ((size_t)(h * 32 + c) * 64 + f * 16 + lr) * 64 + t * 32 + g * 8;
      u16x8 p0 = *(const u16x8*)(kvp0 + off);
      u16x8 p1 = *(const u16x8*)(kvp1 + off);
      u16x8 p2 = *(const u16x8*)(kvp2 + off);
      u16x8 p3 = *(const u16x8*)(kvp3 + off);
      bf16x8 fr;
#pragma unroll
      for (int i = 0; i < 8; ++i)
        fr[i] = (__bf16)((bf2f(p0[i]) + bf2f(p1[i])) + (bf2f(p2[i]) + bf2f(p3[i])));
      bk[f][t] = fr;
    }
  f32x4 ao[4] = {};
#pragma unroll
  for (int t = 0; t < 2; ++t)
#pragma unroll
    for (int f = 0; f < 4; ++f) ao[f] = mfma16(aq[t], bk[f][t], ao[f]);
  float tw[4];
#pragma unroll
  for (int r = 0; r < 4; ++r) tw[r] = 1.f / (1.f + __expf(-tmix[wave * 16 + g * 4 + r]));
#pragma unroll
  for (int f = 0; f < 4; ++f)
#pragma unroll
    for (int r = 0; r < 4; ++r) {
      int s = wave * 16 + g * 4 + r, e = f * 16 + lr;
      float otv = out_t[((size_t)(h * RSEG + c) * 64 + s) * 64 + e];
      float yv = tw[r] * otv + (1.f - tw[r]) * ao[f][r];
      yb[(size_t)(c * 64 + s) * DD + h * DH + e] = f2bf(yv);
    }
}

// ---------------- host launch ----------------
extern "C" void kernel_launch(void* const* d_in, const int* in_sizes, int n_in, void* d_out,
                              int out_size, void* d_ws, size_t ws_size, hipStream_t stream) {
  const float* hs = (const float*)d_in[0];
  const float* Wq = (const float*)d_in[1];
  const float* Wk = (const float*)d_in[2];
  const float* Wv = (const float*)d_in[3];
  const float* Wc = (const float*)d_in[4];
  const float* tmix = (const float*)d_in[5];
  const float* idx_dec = (const float*)d_in[6];
  const float* mega = (const float*)d_in[7];
  char* ws = (char*)d_ws;

  // workspace layout (bytes), max offset 48234496:
  u16* hs_bf = (u16*)(ws + 0);                 // 4 MB   [dead after QKV gemm]
  u16* wq_bf = (u16*)(ws + 4194304);           // 6 MB   [dead after QKV gemm]
  float* dpart = (float*)(ws + 10485760);      // 512 KB [k_tden -> k_tpcs]
  float* wpart = (float*)(ws + 11010048);      // 32 KB  [k_scan -> k_kv]
  u16* wc_bf = (u16*)(ws + 12582912);          // 2 MB   [until final gemm]
  u16* q_bf = (u16*)(ws + 14680064);           // 4 MB   [until k_outlin]
  u16* k_bf = q_bf + (size_t)LL * DD;          // 4 MB   [dead after k_tpcs] -> kvp1
  u16* v_bf = q_bf + 2 * (size_t)LL * DD;      // 4 MB   [dead after transpose] -> kvp0
  u16* kT = (u16*)(ws + 27262976);             // 4 MB
  u16* vT = (u16*)(ws + 31457280);             // 4 MB
  float* pcs = (float*)(ws + 35651584);        // 4 MB   [dead after k_scan] -> kvp2
  float* wbuf = (float*)(ws + 39845888);       // 4 MB
  u16* kvp3 = (u16*)(ws + 44040192);           // 4 MB
  float* out_t = (float*)(ws + 0);             // 8 MB (reuses hs_bf + Wq/Wk region)
  u16* y_bf = (u16*)(ws + 8388608);            // 4 MB (reuses Wv + hole; written by k_outlin)
  u16* kvp0 = v_bf;
  u16* kvp1 = k_bf;
  u16* kvp2 = (u16*)pcs;

  k_castall<<<dim3(6291456 / 4 / 256), 256, 0, stream>>>(hs, Wq, Wk, Wv, Wc, hs_bf, wq_bf, wc_bf);

  k_gemm<128, 128, false><<<dim3(DD / 128, LL / 128, 3), 256, 0, stream>>>(hs_bf, wq_bf, q_bf,
                                                                           nullptr);
  k_tden<<<dim3(3072), 256, 0, stream>>>(k_bf, v_bf, kT, vT, q_bf, dpart);      // 1024 + 2048
  k_tpcs<<<dim3(2560), 256, 0, stream>>>(q_bf, k_bf, vT, dpart, idx_dec, pcs, out_t);  // 2048 + 512

  k_scan<<<dim3(256), 128, 0, stream>>>(pcs, mega, wbuf, wpart);
  k_kv<<<dim3(2048), 256, 0, stream>>>(kT, vT, wbuf, wpart, kvp0, kvp1, kvp2, kvp3);  // 4*32*16
  k_outlin<<<dim3(512), 256, 0, stream>>>(q_bf, kvp0, kvp1, kvp2, kvp3, out_t, tmix, y_bf);
  k_gemm<64, 128, true><<<dim3(DD / 128, LL / 64, 1), 256, 0, stream>>>(y_bf, wc_bf, nullptr,
                                                                        (float*)d_out);
  (void)in_sizes; (void)n_in; (void)out_size; (void)ws_size;
}